// Round 3
// baseline (550.762 us; speedup 1.0000x reference)
//
#include <hip/hip_runtime.h>

#define B_     64
#define DIM_   384
#define RES_   14
#define N_     196
#define HEADS_ 8
#define KD_    32
#define D_     128
#define DH_    1024
#define QK_    256
#define CH_    1536
#define EPS_   1e-5f
#define SCALE_ 0.17677669529663687f   // 32^-0.5
#define NP_    256                    // padded token dim for GEMM tiles
#define MP_    224                    // padded key/token dim for K-side (7*32)

typedef unsigned short u16;
typedef short v8s __attribute__((ext_vector_type(8)));
typedef float v4f __attribute__((ext_vector_type(4)));
typedef u16  v4u __attribute__((ext_vector_type(4)));

static __device__ __forceinline__ u16 f2bf(float f) {
    unsigned int u = __builtin_bit_cast(unsigned int, f);
    u = (u + 0x7fffu + ((u >> 16) & 1u)) >> 16;
    return (u16)u;
}
static __device__ __forceinline__ float bf2f(u16 u) {
    unsigned int x = ((unsigned int)u) << 16;
    return __builtin_bit_cast(float, x);
}
static __device__ __forceinline__ u16 f2h(float f) {
    _Float16 h = (_Float16)f;
    return __builtin_bit_cast(u16, h);
}
static __device__ __forceinline__ float h2f(u16 u) {
    return (float)__builtin_bit_cast(_Float16, u);
}

// workspace layout (u16 element offsets)
#define WB_OFF   0u                      // Wb  [1536][384] bf16
#define WPB_OFF  589824u                 // wpb [384][1024] bf16
#define QT_OFF   983040u                 // qT  [B][256][256] bf16
#define KT_OFF   5177344u                // kT  [B][256][256] bf16
#define VB_OFF   9371648u                // vb  [B][1024][224] bf16
#define PB_OFF   24051712u               // Pb  [B][8][256][224] bf16
#define VLOC_U16 53411840u               // vloc [B][1024][196] fp32 (cast)
#define TAIL_OFF 79101952u               // union: xT [B][256][384] bf16 / Sh [B][8][196][196] fp16 / aoT [B][256][1024] bf16
#define ABT_OFF  98770944u               // abT [196][8] fp32

// ---------------------------------------------------------------------------
// 128x128 MFMA GEMM core: A[M][K] & B[N][K] both K-contiguous bf16.
// 256 threads = 4 waves (2x2); wave -> 64x64 subtile = 16 MFMA / k-step.
// LDS fragment-major [kquad][row][8].
// ---------------------------------------------------------------------------
static __device__ __forceinline__ void gemm_core128(
    const u16* __restrict__ Ag, int ldA,
    const u16* __restrict__ Bg, int ldB,
    int ksteps, u16* sA, u16* sB, v4f acc[4][4], int tid)
{
    const int lane = tid & 63;
    const int w    = tid >> 6;
    const int wm   = (w & 1) * 64;
    const int wn   = (w >> 1) * 64;
    const int quad = lane >> 4;
    const int l16  = lane & 15;
    const int ar = tid & 127;          // staging row
    const int aq = (tid >> 7) * 2;     // staging kquad base {0,2}

    for (int ks = 0; ks < ksteps; ks++) {
        const int k0 = ks * 32;
        v8s a0 = *(const v8s*)(Ag + (size_t)ar * ldA + k0 + (aq + 0) * 8);
        v8s a1 = *(const v8s*)(Ag + (size_t)ar * ldA + k0 + (aq + 1) * 8);
        v8s b0 = *(const v8s*)(Bg + (size_t)ar * ldB + k0 + (aq + 0) * 8);
        v8s b1 = *(const v8s*)(Bg + (size_t)ar * ldB + k0 + (aq + 1) * 8);
        *(v8s*)&sA[(((aq + 0) * 128) + ar) * 8] = a0;
        *(v8s*)&sA[(((aq + 1) * 128) + ar) * 8] = a1;
        *(v8s*)&sB[(((aq + 0) * 128) + ar) * 8] = b0;
        *(v8s*)&sB[(((aq + 1) * 128) + ar) * 8] = b1;
        __syncthreads();
        v8s af[4], bf[4];
        #pragma unroll
        for (int i = 0; i < 4; i++)
            af[i] = *(const v8s*)&sA[((quad * 128) + wm + i * 16 + l16) * 8];
        #pragma unroll
        for (int j = 0; j < 4; j++)
            bf[j] = *(const v8s*)&sB[((quad * 128) + wn + j * 16 + l16) * 8];
        #pragma unroll
        for (int i = 0; i < 4; i++)
            #pragma unroll
            for (int j = 0; j < 4; j++)
                acc[i][j] = __builtin_amdgcn_mfma_f32_16x16x32_bf16(af[i], bf[j], acc[i][j], 0, 0, 0);
        __syncthreads();
    }
}

// ---------------------------------------------------------------------------
// cast weights to bf16 + build abT[idx][h]
// ---------------------------------------------------------------------------
__global__ __launch_bounds__(256) void k_castW(
    const float* __restrict__ wq, const float* __restrict__ wk,
    const float* __restrict__ wv, const float* __restrict__ wp,
    const float* __restrict__ ab,
    u16* __restrict__ Wb, u16* __restrict__ wpb, float* __restrict__ abT)
{
    int i = blockIdx.x * 256 + threadIdx.x;
    if (i < 98304)        Wb[i] = f2bf(wq[i]);
    else if (i < 196608)  Wb[i] = f2bf(wk[i - 98304]);
    else if (i < 589824)  Wb[i] = f2bf(wv[i - 196608]);
    else if (i < 983040)  wpb[i - 589824] = f2bf(wp[i - 589824]);
    else if (i < 983040 + N_ * HEADS_) {
        int j = i - 983040;
        int idx = j >> 3, h = j & 7;
        abT[j] = ab[h * N_ + idx];
    }
}

// ---------------------------------------------------------------------------
// transpose x [B,384,196] fp32 -> xT [B,256,384] bf16 (rows >=196 zero)
// ---------------------------------------------------------------------------
__global__ __launch_bounds__(256) void k_castX(
    const float* __restrict__ x, u16* __restrict__ xT)
{
    __shared__ float T[64][65];
    const int tid = threadIdx.x;
    const int n0 = blockIdx.x * 64;
    const int k0 = blockIdx.y * 64;
    const int b  = blockIdx.z;
    const int c = tid & 63, r4 = tid >> 6;
    #pragma unroll
    for (int i = 0; i < 16; i++) {
        int kr = i * 4 + r4;
        int gn = n0 + c;
        T[kr][c] = (gn < N_) ? x[((size_t)b * DIM_ + k0 + kr) * N_ + gn] : 0.f;
    }
    __syncthreads();
    #pragma unroll
    for (int i = 0; i < 16; i++) {
        int nr = i * 4 + r4;
        xT[((size_t)b * NP_ + n0 + nr) * DIM_ + k0 + c] = f2bf(T[c][nr]);
    }
}

// ---------------------------------------------------------------------------
// K1: QKV GEMM (MFMA 128x128). qT/kT [b][n][256] bf16 (q pre-scaled),
// vb [b][1024][224] bf16 (zero-padded m>=196).
// ---------------------------------------------------------------------------
__global__ __launch_bounds__(256) void k_qkv(
    const u16* __restrict__ Wb, const u16* __restrict__ xT,
    const float* __restrict__ bq, const float* __restrict__ bnq,
    const float* __restrict__ bk, const float* __restrict__ bnk,
    const float* __restrict__ bv, const float* __restrict__ bnv,
    u16* __restrict__ qT, u16* __restrict__ kT, u16* __restrict__ vb)
{
    __shared__ u16 sA[4 * 128 * 8];
    __shared__ u16 sB[4 * 128 * 8];
    const int tid = threadIdx.x;
    const int n0 = blockIdx.x * 128;
    const int m0 = blockIdx.y * 128;
    const int b  = blockIdx.z;
    v4f acc[4][4] = {};
    gemm_core128(Wb + (size_t)m0 * DIM_, DIM_,
                 xT + ((size_t)b * NP_ + n0) * DIM_, DIM_,
                 DIM_ / 32, sA, sB, acc, tid);

    const int lane = tid & 63, w = tid >> 6;
    const int wm = (w & 1) * 64, wn = (w >> 1) * 64;
    const int quad = lane >> 4, l16 = lane & 15;
    #pragma unroll
    for (int i = 0; i < 4; i++) {
        #pragma unroll
        for (int j = 0; j < 4; j++) {
            int rb = m0 + wm + i * 16 + quad * 4;     // channel base (mult of 4)
            int n  = n0 + wn + j * 16 + l16;
            v4f v = acc[i][j];
            if (rb < 256) {            // q segment
                v4u u;
                #pragma unroll
                for (int r = 0; r < 4; r++) {
                    int c = rb + r;
                    float s = bnq[c] * rsqrtf(bnq[3 * 256 + c] + EPS_);
                    float t = (bq[c] - bnq[2 * 256 + c]) * s + bnq[256 + c];
                    u[r] = f2bf((v[r] * s + t) * SCALE_);
                }
                *(v4u*)&qT[((size_t)b * NP_ + n) * 256 + rb] = u;
            } else if (rb < 512) {     // k segment
                v4u u;
                #pragma unroll
                for (int r = 0; r < 4; r++) {
                    int c = rb - 256 + r;
                    float s = bnk[c] * rsqrtf(bnk[3 * 256 + c] + EPS_);
                    float t = (bk[c] - bnk[2 * 256 + c]) * s + bnk[256 + c];
                    u[r] = f2bf(v[r] * s + t);
                }
                *(v4u*)&kT[((size_t)b * NP_ + n) * 256 + (rb - 256)] = u;
            } else {                   // v segment
                #pragma unroll
                for (int r = 0; r < 4; r++) {
                    int c = rb - 512 + r;
                    float s = bnv[c] * rsqrtf(bnv[3 * DH_ + c] + EPS_);
                    float t = (bv[c] - bnv[2 * DH_ + c]) * s + bnv[DH_ + c];
                    if (n < MP_)
                        vb[((size_t)b * DH_ + c) * MP_ + n] = (n < N_) ? f2bf(v[r] * s + t) : (u16)0;
                }
            }
        }
    }
}

// ---------------------------------------------------------------------------
// K2: depthwise 3x3 conv on vb (bf16) + bias + BN -> vloc fp32
// ---------------------------------------------------------------------------
__global__ __launch_bounds__(256) void k_dwconv(
    const u16* __restrict__ vb, const float* __restrict__ wvl,
    const float* __restrict__ bvl, const float* __restrict__ bnvl,
    float* __restrict__ vloc)
{
    int idx = blockIdx.x * 256 + threadIdx.x;
    if (idx >= B_ * DH_ * N_) return;
    int n = idx % N_;
    int t = idx / N_;
    int c = t % DH_;
    int b = t / DH_;
    int y = n / RES_, x0 = n % RES_;
    const u16* v = vb + ((size_t)b * DH_ + c) * MP_;
    const float* wgt = wvl + c * 9;
    float s = 0.f;
    #pragma unroll
    for (int ky = 0; ky < 3; ky++) {
        int yy = y + ky - 1;
        if (yy < 0 || yy >= RES_) continue;
        #pragma unroll
        for (int kx = 0; kx < 3; kx++) {
            int xx = x0 + kx - 1;
            if (xx < 0 || xx >= RES_) continue;
            s += bf2f(v[yy * RES_ + xx]) * wgt[ky * 3 + kx];
        }
    }
    s += bvl[c];
    float sc = bnvl[c] * rsqrtf(bnvl[3 * DH_ + c] + EPS_);
    vloc[idx] = (s - bnvl[2 * DH_ + c]) * sc + bnvl[DH_ + c];
}

// ---------------------------------------------------------------------------
// K3: score GEMM per (b,h) — LDS-free. qT/kT rows are already MFMA-fragment-
// shaped; each wave owns one 16-query tile, loops 13 key tiles. -> Sh fp16
// ---------------------------------------------------------------------------
__global__ __launch_bounds__(256) void k_score(
    const u16* __restrict__ qT, const u16* __restrict__ kT,
    u16* __restrict__ Sh)
{
    const int tid = threadIdx.x;
    const int w = tid >> 6, lane = tid & 63;
    const int quad = lane >> 4, l16 = lane & 15;
    const int b = blockIdx.z, h = blockIdx.y;
    const int qt = blockIdx.x * 4 + w;
    if (qt >= 13) return;   // wave-uniform

    v8s a = *(const v8s*)(qT + ((size_t)b * NP_ + qt * 16 + l16) * 256 + h * KD_ + quad * 8);
    const int q0 = qt * 16 + quad * 4;
    u16* So = Sh + ((size_t)(b * HEADS_ + h) * N_) * N_;

    for (int mt = 0; mt < 13; mt++) {
        v8s bfr = *(const v8s*)(kT + ((size_t)b * NP_ + mt * 16 + l16) * 256 + h * KD_ + quad * 8);
        v4f acc = {};
        acc = __builtin_amdgcn_mfma_f32_16x16x32_bf16(a, bfr, acc, 0, 0, 0);
        int m = mt * 16 + l16;
        if (m < N_) {
            #pragma unroll
            for (int r = 0; r < 4; r++) {
                int q = q0 + r;
                if (q < N_) So[(size_t)q * N_ + m] = f2h(acc[r]);
            }
        }
    }
}

// ---------------------------------------------------------------------------
// K4: register-resident softmax/talking-heads. Block = (b,n); thread owns m.
// TH1/TH2 in registers; softmax via wave shuffles + tiny LDS combine.
// ---------------------------------------------------------------------------
__global__ __launch_bounds__(256) void k_soft(
    const u16* __restrict__ Sh,
    const float* __restrict__ th1w, const float* __restrict__ th1b,
    const float* __restrict__ th2w, const float* __restrict__ th2b,
    const float* __restrict__ abT, const int* __restrict__ bidx,
    u16* __restrict__ Pb)
{
    __shared__ float red[2][4][8];
    const int tid = threadIdx.x;
    const int m = tid;
    const int w = tid >> 6;
    const int n = blockIdx.x, b = blockIdx.y;
    const bool act = (m < N_);

    float S[8];
    if (act) {
        int idx = bidx[n * N_ + m];
        v4f ab0 = *(const v4f*)&abT[idx * 8];
        v4f ab1 = *(const v4f*)&abT[idx * 8 + 4];
        #pragma unroll
        for (int h = 0; h < 8; h++) {
            float bias = (h < 4) ? ab0[h] : ab1[h - 4];
            S[h] = h2f(Sh[((size_t)(b * HEADS_ + h) * N_ + n) * N_ + m]) + bias;
        }
    } else {
        #pragma unroll
        for (int h = 0; h < 8; h++) S[h] = 0.f;
    }

    float A[8];
    #pragma unroll
    for (int o = 0; o < 8; o++) {
        float a = th1b[o];
        #pragma unroll
        for (int h = 0; h < 8; h++) a += th1w[o * 8 + h] * S[h];
        A[o] = act ? a : -1e30f;
    }

    // max reduce
    #pragma unroll
    for (int o = 0; o < 8; o++) {
        float v = A[o];
        #pragma unroll
        for (int off = 32; off > 0; off >>= 1) v = fmaxf(v, __shfl_xor(v, off, 64));
        if ((tid & 63) == 0) red[0][w][o] = v;
    }
    __syncthreads();
    float e[8];
    #pragma unroll
    for (int o = 0; o < 8; o++) {
        float mx = fmaxf(fmaxf(red[0][0][o], red[0][1][o]),
                         fmaxf(red[0][2][o], red[0][3][o]));
        e[o] = act ? __expf(A[o] - mx) : 0.f;
    }
    // sum reduce
    #pragma unroll
    for (int o = 0; o < 8; o++) {
        float v = e[o];
        #pragma unroll
        for (int off = 32; off > 0; off >>= 1) v += __shfl_xor(v, off, 64);
        if ((tid & 63) == 0) red[1][w][o] = v;
    }
    __syncthreads();
    #pragma unroll
    for (int o = 0; o < 8; o++) {
        float sm = (red[1][0][o] + red[1][1][o]) + (red[1][2][o] + red[1][3][o]);
        e[o] *= (1.f / sm);
    }
    // TH2 + store
    if (m < MP_) {
        #pragma unroll
        for (int o = 0; o < 8; o++) {
            float p = th2b[o];
            #pragma unroll
            for (int h = 0; h < 8; h++) p += th2w[o * 8 + h] * e[h];
            Pb[((size_t)(b * HEADS_ + o) * NP_ + n) * MP_ + m] = act ? f2bf(p) : (u16)0;
        }
    }
}

// ---------------------------------------------------------------------------
// K5: attn @ V (MFMA 128x128, K=224) + v_local + relu -> aoT [b][n][1024] bf16
// ---------------------------------------------------------------------------
__global__ __launch_bounds__(256) void k_av(
    const u16* __restrict__ vb, const u16* __restrict__ Pb,
    const float* __restrict__ vloc, u16* __restrict__ aoT)
{
    __shared__ u16 sA[4 * 128 * 8];
    __shared__ u16 sB[4 * 128 * 8];
    const int tid = threadIdx.x;
    const int n0 = blockIdx.x * 128;
    const int o  = blockIdx.y;
    const int b  = blockIdx.z;
    v4f acc[4][4] = {};
    gemm_core128(vb + ((size_t)b * DH_ + o * D_) * MP_, MP_,
                 Pb + (((size_t)b * HEADS_ + o) * NP_ + n0) * MP_, MP_,
                 MP_ / 32, sA, sB, acc, tid);

    const int lane = tid & 63, w = tid >> 6;
    const int wm = (w & 1) * 64, wn = (w >> 1) * 64;
    const int quad = lane >> 4, l16 = lane & 15;
    #pragma unroll
    for (int i = 0; i < 4; i++) {
        #pragma unroll
        for (int j = 0; j < 4; j++) {
            int rb = wm + i * 16 + quad * 4;         // e base
            int n  = n0 + wn + j * 16 + l16;
            v4u u;
            #pragma unroll
            for (int r = 0; r < 4; r++) {
                u16 outv = 0;
                if (n < N_) {
                    int c = o * D_ + rb + r;
                    float val = acc[i][j][r] + vloc[((size_t)b * DH_ + c) * N_ + n];
                    outv = f2bf(fmaxf(val, 0.f));
                }
                u[r] = outv;
            }
            *(v4u*)&aoT[((size_t)b * NP_ + n) * DH_ + o * D_ + rb] = u;
        }
    }
}

// ---------------------------------------------------------------------------
// K6: projection GEMM (MFMA 128x128, K=1024) + bias + BN -> out fp32
// ---------------------------------------------------------------------------
__global__ __launch_bounds__(256) void k_proj(
    const u16* __restrict__ wpb, const u16* __restrict__ aoT,
    const float* __restrict__ bp, const float* __restrict__ bnp,
    float* __restrict__ out)
{
    __shared__ u16 sA[4 * 128 * 8];
    __shared__ u16 sB[4 * 128 * 8];
    const int tid = threadIdx.x;
    const int n0 = blockIdx.x * 128;
    const int m0 = blockIdx.y * 128;
    const int b  = blockIdx.z;
    v4f acc[4][4] = {};
    gemm_core128(wpb + (size_t)m0 * DH_, DH_,
                 aoT + ((size_t)b * NP_ + n0) * DH_, DH_,
                 DH_ / 32, sA, sB, acc, tid);

    const int lane = tid & 63, w = tid >> 6;
    const int wm = (w & 1) * 64, wn = (w >> 1) * 64;
    const int quad = lane >> 4, l16 = lane & 15;
    #pragma unroll
    for (int i = 0; i < 4; i++) {
        #pragma unroll
        for (int j = 0; j < 4; j++) {
            int rb = m0 + wm + i * 16 + quad * 4;
            int n  = n0 + wn + j * 16 + l16;
            if (n < N_) {
                #pragma unroll
                for (int r = 0; r < 4; r++) {
                    int p = rb + r;
                    float s = bnp[p] * rsqrtf(bnp[3 * DIM_ + p] + EPS_);
                    float t = (bp[p] - bnp[2 * DIM_ + p]) * s + bnp[DIM_ + p];
                    out[((size_t)b * DIM_ + p) * N_ + n] = acc[i][j][r] * s + t;
                }
            }
        }
    }
}

// ---------------------------------------------------------------------------
extern "C" void kernel_launch(void* const* d_in, const int* in_sizes, int n_in,
                              void* d_out, int out_size, void* d_ws, size_t ws_size,
                              hipStream_t stream)
{
    const float* x    = (const float*)d_in[0];
    const float* wq   = (const float*)d_in[1];
    const float* bq   = (const float*)d_in[2];
    const float* bnq  = (const float*)d_in[3];
    const float* wk   = (const float*)d_in[4];
    const float* bk   = (const float*)d_in[5];
    const float* bnk  = (const float*)d_in[6];
    const float* wv   = (const float*)d_in[7];
    const float* bv   = (const float*)d_in[8];
    const float* bnv  = (const float*)d_in[9];
    const float* wvl  = (const float*)d_in[10];
    const float* bvl  = (const float*)d_in[11];
    const float* bnvl = (const float*)d_in[12];
    const float* th1w = (const float*)d_in[13];
    const float* th1b = (const float*)d_in[14];
    const float* th2w = (const float*)d_in[15];
    const float* th2b = (const float*)d_in[16];
    const float* wp   = (const float*)d_in[17];
    const float* bp   = (const float*)d_in[18];
    const float* bnp  = (const float*)d_in[19];
    const float* ab   = (const float*)d_in[20];
    const int*   bidx = (const int*)d_in[21];
    float* out = (float*)d_out;

    u16* wsb  = (u16*)d_ws;
    u16* Wb   = wsb + WB_OFF;
    u16* wpb  = wsb + WPB_OFF;
    u16* qT   = wsb + QT_OFF;
    u16* kT   = wsb + KT_OFF;
    u16* vb   = wsb + VB_OFF;
    u16* Pb   = wsb + PB_OFF;
    float* vloc = (float*)(wsb + VLOC_U16);
    u16* xT   = wsb + TAIL_OFF;   // aliased: xT -> Sh -> aoT (disjoint lifetimes)
    u16* Sh   = wsb + TAIL_OFF;
    u16* aoT  = wsb + TAIL_OFF;
    float* abT = (float*)(wsb + ABT_OFF);

    k_castW<<<dim3(3847), 256, 0, stream>>>(wq, wk, wv, wp, ab, Wb, wpb, abT);
    k_castX<<<dim3(4, 6, B_), 256, 0, stream>>>(x, xT);
    k_qkv<<<dim3(2, 12, B_), 256, 0, stream>>>(Wb, xT, bq, bnq, bk, bnk, bv, bnv, qT, kT, vb);
    k_dwconv<<<dim3((B_ * DH_ * N_ + 255) / 256), 256, 0, stream>>>(vb, wvl, bvl, bnvl, vloc);
    k_score<<<dim3(4, HEADS_, B_), 256, 0, stream>>>(qT, kT, Sh);
    k_soft<<<dim3(N_, B_), 256, 0, stream>>>(Sh, th1w, th1b, th2w, th2b, abT, bidx, Pb);
    k_av<<<dim3(2, HEADS_, B_), 256, 0, stream>>>(vb, Pb, vloc, aoT);
    k_proj<<<dim3(2, 3, B_), 256, 0, stream>>>(wpb, aoT, bp, bnp, out);
}

// Round 4
// 465.950 us; speedup vs baseline: 1.1820x; 1.1820x over previous
//
#include <hip/hip_runtime.h>

#define B_     64
#define DIM_   384
#define RES_   14
#define N_     196
#define HEADS_ 8
#define KD_    32
#define D_     128
#define DH_    1024
#define QK_    256
#define CH_    1536
#define EPS_   1e-5f
#define SCALE_ 0.17677669529663687f   // 32^-0.5

typedef unsigned short u16;
typedef short v8s __attribute__((ext_vector_type(8)));
typedef float v4f __attribute__((ext_vector_type(4)));
typedef u16  v4u __attribute__((ext_vector_type(4)));

static __device__ __forceinline__ u16 f2bf(float f) {
    unsigned int u = __builtin_bit_cast(unsigned int, f);
    u = (u + 0x7fffu + ((u >> 16) & 1u)) >> 16;
    return (u16)u;
}
static __device__ __forceinline__ float bf2f(u16 u) {
    unsigned int x = ((unsigned int)u) << 16;
    return __builtin_bit_cast(float, x);
}
static __device__ __forceinline__ u16 f2h(float f) {
    _Float16 h = (_Float16)f;
    return __builtin_bit_cast(u16, h);
}
static __device__ __forceinline__ float h2f(u16 u) {
    return (float)__builtin_bit_cast(_Float16, u);
}

// async global->LDS, 16B per lane; LDS dest = wave-uniform base + lane*16
static __device__ __forceinline__ void gload_lds16(const u16* g, u16* l) {
    __builtin_amdgcn_global_load_lds(
        (const __attribute__((address_space(1))) void*)g,
        (__attribute__((address_space(3))) void*)l, 16, 0, 0);
}

// workspace layout (u16 element offsets)
// GEMM operand images: [kstep][kquad(4)][row(128)][8] = 4096 elems (8KB)/kstep
#define WBI_OFF  0u          // Wb  image: 12 mtiles x 12 ksteps      (589824)
#define WPI_OFF  589824u     // wp  image: 3 mtiles x 32 ksteps       (393216)
#define QI_OFF   983040u     // qT  [B][8][256][32]                   (4194304)
#define KI_OFF   5177344u    // kT  [B][8][256][32]                   (4194304)
#define VI_OFF   9371648u    // v   image: [B][8] x 7 ksteps          (14680064)
#define PBI_OFF  24051712u   // P   image: [B][8][nt2] x 7 ksteps     (29360128)
#define VLOC_U16 53411840u   // vloc [B][1024][196] fp32              (25690112 u16)
#define TAIL_OFF 79101952u   // union: xI (6291456) / Sh fp16 (19668992) / aoI (16777216)
#define TB_OFF   98770944u   // BN tables fp32[5888]: sQ,tQ,sK,tK @0/256/512/768; sV@1024,tV@2048; sP@3072,tP@3456; sVL@3840,tVL@4864
#define ABT_OFF  98782720u   // abT [196][8] fp32

// ---------------------------------------------------------------------------
// 128x128 MFMA GEMM core, operands pre-packed as LDS images.
// 4 waves (2x2), 64x64 subtile each, 16 MFMA/k-step/wave.
// Staging: global_load_lds dwordx4, fully coalesced (1KB/wave-instr).
// ---------------------------------------------------------------------------
static __device__ __forceinline__ void gemm_core_g(
    const u16* __restrict__ Aimg, const u16* __restrict__ Bimg,
    int ksteps, u16* sA, u16* sB, v4f acc[4][4], int tid)
{
    const int lane = tid & 63;
    const int w    = tid >> 6;
    const int wm   = (w & 1) * 64;
    const int wn   = (w >> 1) * 64;
    const int quad = lane >> 4;
    const int l16  = lane & 15;
    const int la   = lane * 8;
    const int c0   = w * 1024;   // wave's two 512-elem chunks

    for (int ks = 0; ks < ksteps; ks++) {
        const u16* ga = Aimg + ks * 4096 + la;
        const u16* gb = Bimg + ks * 4096 + la;
        gload_lds16(ga + c0,       sA + c0);
        gload_lds16(ga + c0 + 512, sA + c0 + 512);
        gload_lds16(gb + c0,       sB + c0);
        gload_lds16(gb + c0 + 512, sB + c0 + 512);
        __syncthreads();
        v8s af[4], bf[4];
        #pragma unroll
        for (int i = 0; i < 4; i++)
            af[i] = *(const v8s*)&sA[(quad * 128 + wm + i * 16 + l16) * 8];
        #pragma unroll
        for (int j = 0; j < 4; j++)
            bf[j] = *(const v8s*)&sB[(quad * 128 + wn + j * 16 + l16) * 8];
        #pragma unroll
        for (int i = 0; i < 4; i++)
            #pragma unroll
            for (int j = 0; j < 4; j++)
                acc[i][j] = __builtin_amdgcn_mfma_f32_16x16x32_bf16(af[i], bf[j], acc[i][j], 0, 0, 0);
        __syncthreads();
    }
}

// ---------------------------------------------------------------------------
// pack weights into tile images + abT + BN scale/shift tables
// ---------------------------------------------------------------------------
__global__ __launch_bounds__(256) void k_castW(
    const float* __restrict__ wq, const float* __restrict__ wk,
    const float* __restrict__ wv, const float* __restrict__ wp,
    const float* __restrict__ ab,
    const float* __restrict__ bq, const float* __restrict__ bnq,
    const float* __restrict__ bk, const float* __restrict__ bnk,
    const float* __restrict__ bv, const float* __restrict__ bnv,
    const float* __restrict__ bp, const float* __restrict__ bnp,
    const float* __restrict__ bvl, const float* __restrict__ bnvl,
    u16* __restrict__ WbI, u16* __restrict__ WpI,
    float* __restrict__ abT, float* __restrict__ TB)
{
    int i = blockIdx.x * 256 + threadIdx.x;
    if (i < 589824) {           // qkv weight image
        int mt = i / 49152, rem = i % 49152;
        int ks = rem >> 12, r2 = rem & 4095;
        int q = r2 >> 10, row = (r2 >> 3) & 127, e = r2 & 7;
        int c = mt * 128 + row, k = ks * 32 + q * 8 + e;
        float v = (c < 256) ? wq[c * 384 + k]
                : (c < 512) ? wk[(c - 256) * 384 + k]
                            : wv[(size_t)(c - 512) * 384 + k];
        WbI[i] = f2bf(v);
    } else if (i < 983040) {    // proj weight image
        int j = i - 589824;
        int mt = j >> 17, rem = j & 131071;
        int ks = rem >> 12, r2 = rem & 4095;
        int q = r2 >> 10, row = (r2 >> 3) & 127, e = r2 & 7;
        int p = mt * 128 + row, k = ks * 32 + q * 8 + e;
        WpI[j] = f2bf(wp[(size_t)p * 1024 + k]);
    } else if (i < 984608) {    // abT
        int j = i - 983040;
        abT[j] = ab[(j & 7) * N_ + (j >> 3)];
    } else if (i < 987552) {    // BN tables
        int j = i - 984608;
        if (j < 256) {
            int c = j;
            float s = bnq[c] * rsqrtf(bnq[768 + c] + EPS_);
            float t = (bq[c] - bnq[512 + c]) * s + bnq[256 + c];
            TB[c] = s * SCALE_; TB[256 + c] = t * SCALE_;
        } else if (j < 512) {
            int c = j - 256;
            float s = bnk[c] * rsqrtf(bnk[768 + c] + EPS_);
            float t = (bk[c] - bnk[512 + c]) * s + bnk[256 + c];
            TB[512 + c] = s; TB[768 + c] = t;
        } else if (j < 1536) {
            int c = j - 512;
            float s = bnv[c] * rsqrtf(bnv[3072 + c] + EPS_);
            float t = (bv[c] - bnv[2048 + c]) * s + bnv[1024 + c];
            TB[1024 + c] = s; TB[2048 + c] = t;
        } else if (j < 1920) {
            int c = j - 1536;
            float s = bnp[c] * rsqrtf(bnp[1152 + c] + EPS_);
            float t = (bp[c] - bnp[768 + c]) * s + bnp[384 + c];
            TB[3072 + c] = s; TB[3456 + c] = t;
        } else {
            int c = j - 1920;
            float s = bnvl[c] * rsqrtf(bnvl[3072 + c] + EPS_);
            float t = (bvl[c] - bnvl[2048 + c]) * s + bnvl[1024 + c];
            TB[3840 + c] = s; TB[4864 + c] = t;
        }
    }
}

// ---------------------------------------------------------------------------
// x [B,384,196] fp32 -> xI image [B][nt2][12 ksteps][4096] bf16 (n>=196 zero)
// ---------------------------------------------------------------------------
__global__ __launch_bounds__(256) void k_castX(
    const float* __restrict__ x, u16* __restrict__ xI)
{
    __shared__ float T[64][65];
    const int tid = threadIdx.x;
    const int n0 = blockIdx.x * 64;
    const int k0 = blockIdx.y * 64;
    const int b  = blockIdx.z;
    const int c = tid & 63, r4 = tid >> 6;
    #pragma unroll
    for (int i = 0; i < 16; i++) {
        int kr = i * 4 + r4;
        int gn = n0 + c;
        T[kr][c] = (gn < N_) ? x[((size_t)b * DIM_ + k0 + kr) * N_ + gn] : 0.f;
    }
    __syncthreads();
    #pragma unroll
    for (int it = 0; it < 16; it++) {
        int j = it * 256 + tid;
        int kk = j & 63, nn = j >> 6;
        int k = k0 + kk, n = n0 + nn;
        xI[(size_t)b * 98304 + (n >> 7) * 49152 + (k >> 5) * 4096
           + ((k >> 3) & 3) * 1024 + (n & 127) * 8 + (k & 7)] = f2bf(T[kk][nn]);
    }
}

// ---------------------------------------------------------------------------
// K1: QKV GEMM. Outputs: qI/kI [b][h][256][32] bf16 (q pre-scaled),
// vI image per (b,o), 7 ksteps (n>=196 zero).
// ---------------------------------------------------------------------------
__global__ __launch_bounds__(256) void k_qkv(
    const u16* __restrict__ WbI, const u16* __restrict__ xI,
    const float* __restrict__ TB,
    u16* __restrict__ qI, u16* __restrict__ kI, u16* __restrict__ vI)
{
    __shared__ u16 sA[4096];
    __shared__ u16 sB[4096];
    const int tid = threadIdx.x;
    const int nt = blockIdx.x;
    const int mt = blockIdx.y;
    const int b  = blockIdx.z;
    v4f acc[4][4] = {};
    gemm_core_g(WbI + (size_t)mt * 49152,
                xI + ((size_t)b * 2 + nt) * 49152, 12, sA, sB, acc, tid);

    const int lane = tid & 63, w = tid >> 6;
    const int wm = (w & 1) * 64, wn = (w >> 1) * 64;
    const int quad = lane >> 4, l16 = lane & 15;
    #pragma unroll
    for (int i = 0; i < 4; i++) {
        #pragma unroll
        for (int j = 0; j < 4; j++) {
            int gc = mt * 128 + wm + i * 16 + quad * 4;  // global channel base
            int n  = nt * 128 + wn + j * 16 + l16;       // token (0..255)
            v4f v = acc[i][j];
            if (gc < 256) {            // q
                v4f s = *(const v4f*)&TB[gc];
                v4f t = *(const v4f*)&TB[256 + gc];
                v4u u;
                #pragma unroll
                for (int r = 0; r < 4; r++) u[r] = f2bf(v[r] * s[r] + t[r]);
                *(v4u*)&qI[((size_t)(b * 8 + (gc >> 5)) * 256 + n) * 32 + (gc & 31)] = u;
            } else if (gc < 512) {     // k
                int c = gc - 256;
                v4f s = *(const v4f*)&TB[512 + c];
                v4f t = *(const v4f*)&TB[768 + c];
                v4u u;
                #pragma unroll
                for (int r = 0; r < 4; r++) u[r] = f2bf(v[r] * s[r] + t[r]);
                *(v4u*)&kI[((size_t)(b * 8 + (c >> 5)) * 256 + n) * 32 + (c & 31)] = u;
            } else {                   // v -> image (row = e, col = n as k-dim)
                int c = gc - 512;      // 0..1023
                if (n < 224) {
                    int o = c >> 7, e = c & 127;
                    u16* base = vI + ((size_t)(b * 8 + o) * 7 + (n >> 5)) * 4096
                                + ((n >> 3) & 3) * 1024 + (n & 7);
                    #pragma unroll
                    for (int r = 0; r < 4; r++) {
                        u16 outv = 0;
                        if (n < N_) outv = f2bf(v[r] * TB[1024 + c + r] + TB[2048 + c + r]);
                        base[(e + r) * 8] = outv;
                    }
                }
            }
        }
    }
}

// ---------------------------------------------------------------------------
// K2: depthwise 3x3 conv on vI (image layout) -> vloc fp32 [b][c][196]
// ---------------------------------------------------------------------------
__global__ __launch_bounds__(256) void k_dwconv(
    const u16* __restrict__ vI, const float* __restrict__ wvl,
    const float* __restrict__ TB, float* __restrict__ vloc)
{
    int idx = blockIdx.x * 256 + threadIdx.x;
    if (idx >= B_ * DH_ * N_) return;
    int n = idx % N_;
    int t = idx / N_;
    int c = t % DH_;
    int b = t / DH_;
    int y = n / RES_, x0 = n % RES_;
    int o = c >> 7, e = c & 127;
    const u16* base = vI + (size_t)(b * 8 + o) * 28672 + e * 8;
    const float* wgt = wvl + c * 9;
    float s = 0.f;
    #pragma unroll
    for (int ky = 0; ky < 3; ky++) {
        int yy = y + ky - 1;
        if (yy < 0 || yy >= RES_) continue;
        #pragma unroll
        for (int kx = 0; kx < 3; kx++) {
            int xx = x0 + kx - 1;
            if (xx < 0 || xx >= RES_) continue;
            int m = yy * RES_ + xx;
            s += bf2f(base[(m >> 5) * 4096 + ((m >> 3) & 3) * 1024 + (m & 7)]) * wgt[ky * 3 + kx];
        }
    }
    vloc[idx] = s * TB[3840 + c] + TB[4864 + c];
}

// ---------------------------------------------------------------------------
// K3: score GEMM per (b,h), LDS-free; qI/kI rows are MFMA fragments
// (fully contiguous 1KB loads). -> Sh fp16 [b][h][196][196]
// ---------------------------------------------------------------------------
__global__ __launch_bounds__(256) void k_score(
    const u16* __restrict__ qI, const u16* __restrict__ kI,
    u16* __restrict__ Sh)
{
    const int tid = threadIdx.x;
    const int w = tid >> 6, lane = tid & 63;
    const int quad = lane >> 4, l16 = lane & 15;
    const int b = blockIdx.z, h = blockIdx.y;
    const int qt = blockIdx.x * 4 + w;
    if (qt >= 13) return;   // wave-uniform

    const u16* qb = qI + (size_t)(b * 8 + h) * 8192;
    const u16* kb = kI + (size_t)(b * 8 + h) * 8192;
    v8s a = *(const v8s*)&qb[(qt * 16 + l16) * 32 + quad * 8];
    const int q0 = qt * 16 + quad * 4;
    u16* So = Sh + (size_t)(b * 8 + h) * N_ * N_;

    for (int mt = 0; mt < 13; mt++) {
        v8s bfr = *(const v8s*)&kb[(mt * 16 + l16) * 32 + quad * 8];
        v4f acc = {};
        acc = __builtin_amdgcn_mfma_f32_16x16x32_bf16(a, bfr, acc, 0, 0, 0);
        int m = mt * 16 + l16;
        if (m < N_) {
            #pragma unroll
            for (int r = 0; r < 4; r++) {
                int q = q0 + r;
                if (q < N_) So[(size_t)q * N_ + m] = f2h(acc[r]);
            }
        }
    }
}

// ---------------------------------------------------------------------------
// K4: register-resident softmax/talking-heads -> P image [b][o][nt][7ks][4096]
// ---------------------------------------------------------------------------
__global__ __launch_bounds__(256) void k_soft(
    const u16* __restrict__ Sh,
    const float* __restrict__ th1w, const float* __restrict__ th1b,
    const float* __restrict__ th2w, const float* __restrict__ th2b,
    const float* __restrict__ abT, const int* __restrict__ bidx,
    u16* __restrict__ PbI)
{
    __shared__ float red[2][4][8];
    const int tid = threadIdx.x;
    const int m = tid;
    const int w = tid >> 6;
    const int n = blockIdx.x, b = blockIdx.y;
    const bool act = (m < N_);

    float S[8];
    if (act) {
        int idx = bidx[n * N_ + m];
        v4f ab0 = *(const v4f*)&abT[idx * 8];
        v4f ab1 = *(const v4f*)&abT[idx * 8 + 4];
        #pragma unroll
        for (int h = 0; h < 8; h++) {
            float bias = (h < 4) ? ab0[h] : ab1[h - 4];
            S[h] = h2f(Sh[((size_t)(b * 8 + h) * N_ + n) * N_ + m]) + bias;
        }
    } else {
        #pragma unroll
        for (int h = 0; h < 8; h++) S[h] = 0.f;
    }

    float A[8];
    #pragma unroll
    for (int o = 0; o < 8; o++) {
        float a = th1b[o];
        #pragma unroll
        for (int h = 0; h < 8; h++) a += th1w[o * 8 + h] * S[h];
        A[o] = act ? a : -1e30f;
    }

    #pragma unroll
    for (int o = 0; o < 8; o++) {
        float v = A[o];
        #pragma unroll
        for (int off = 32; off > 0; off >>= 1) v = fmaxf(v, __shfl_xor(v, off, 64));
        if ((tid & 63) == 0) red[0][w][o] = v;
    }
    __syncthreads();
    float e[8];
    #pragma unroll
    for (int o = 0; o < 8; o++) {
        float mx = fmaxf(fmaxf(red[0][0][o], red[0][1][o]),
                         fmaxf(red[0][2][o], red[0][3][o]));
        e[o] = act ? __expf(A[o] - mx) : 0.f;
    }
    #pragma unroll
    for (int o = 0; o < 8; o++) {
        float v = e[o];
        #pragma unroll
        for (int off = 32; off > 0; off >>= 1) v += __shfl_xor(v, off, 64);
        if ((tid & 63) == 0) red[1][w][o] = v;
    }
    __syncthreads();
    #pragma unroll
    for (int o = 0; o < 8; o++) {
        float sm = (red[1][0][o] + red[1][1][o]) + (red[1][2][o] + red[1][3][o]);
        e[o] *= (1.f / sm);
    }
    if (m < 224) {
        size_t rowoff = ((size_t)(m >> 5)) * 4096 + ((m >> 3) & 3) * 1024 + (n & 127) * 8 + (m & 7);
        #pragma unroll
        for (int o = 0; o < 8; o++) {
            float p = th2b[o];
            #pragma unroll
            for (int h = 0; h < 8; h++) p += th2w[o * 8 + h] * e[h];
            PbI[((size_t)(b * 8 + o) * 2 + (n >> 7)) * 28672 + rowoff] = act ? f2bf(p) : (u16)0;
        }
    }
}

// ---------------------------------------------------------------------------
// K5: attn @ V (K=224, 7 ksteps) + v_local + relu -> aoI image
// ---------------------------------------------------------------------------
__global__ __launch_bounds__(256) void k_av(
    const u16* __restrict__ vI, const u16* __restrict__ PbI,
    const float* __restrict__ vloc, u16* __restrict__ aoI)
{
    __shared__ u16 sA[4096];
    __shared__ u16 sB[4096];
    const int tid = threadIdx.x;
    const int nt = blockIdx.x;
    const int o  = blockIdx.y;
    const int b  = blockIdx.z;
    v4f acc[4][4] = {};
    gemm_core_g(vI + (size_t)(b * 8 + o) * 28672,
                PbI + ((size_t)(b * 8 + o) * 2 + nt) * 28672, 7, sA, sB, acc, tid);

    const int lane = tid & 63, w = tid >> 6;
    const int wm = (w & 1) * 64, wn = (w >> 1) * 64;
    const int quad = lane >> 4, l16 = lane & 15;
    #pragma unroll
    for (int i = 0; i < 4; i++) {
        #pragma unroll
        for (int j = 0; j < 4; j++) {
            int lr = wm + i * 16 + quad * 4;        // e base
            int c0 = o * 128 + lr;                  // global k-index base
            int n  = nt * 128 + wn + j * 16 + l16;  // token (0..255)
            v4u u;
            #pragma unroll
            for (int r = 0; r < 4; r++) {
                u16 outv = 0;
                if (n < N_) {
                    float val = acc[i][j][r] + vloc[((size_t)b * DH_ + c0 + r) * N_ + n];
                    outv = f2bf(fmaxf(val, 0.f));
                }
                u[r] = outv;
            }
            *(v4u*)&aoI[((size_t)(b * 2 + nt) * 32 + (c0 >> 5)) * 4096
                        + ((c0 >> 3) & 3) * 1024 + (n & 127) * 8 + (c0 & 7)] = u;
        }
    }
}

// ---------------------------------------------------------------------------
// K6: projection GEMM (K=1024, 32 ksteps) + BN -> out fp32
// ---------------------------------------------------------------------------
__global__ __launch_bounds__(256) void k_proj(
    const u16* __restrict__ WpI, const u16* __restrict__ aoI,
    const float* __restrict__ TB, float* __restrict__ out)
{
    __shared__ u16 sA[4096];
    __shared__ u16 sB[4096];
    const int tid = threadIdx.x;
    const int nt = blockIdx.x;
    const int mt = blockIdx.y;
    const int b  = blockIdx.z;
    v4f acc[4][4] = {};
    gemm_core_g(WpI + (size_t)mt * 131072,
                aoI + (size_t)(b * 2 + nt) * 131072, 32, sA, sB, acc, tid);

    const int lane = tid & 63, w = tid >> 6;
    const int wm = (w & 1) * 64, wn = (w >> 1) * 64;
    const int quad = lane >> 4, l16 = lane & 15;
    #pragma unroll
    for (int i = 0; i < 4; i++) {
        #pragma unroll
        for (int j = 0; j < 4; j++) {
            int p0 = mt * 128 + wm + i * 16 + quad * 4;
            int n  = nt * 128 + wn + j * 16 + l16;
            if (n < N_) {
                v4f s = *(const v4f*)&TB[3072 + p0];
                v4f t = *(const v4f*)&TB[3456 + p0];
                #pragma unroll
                for (int r = 0; r < 4; r++)
                    out[((size_t)b * DIM_ + p0 + r) * N_ + n] = acc[i][j][r] * s[r] + t[r];
            }
        }
    }
}

// ---------------------------------------------------------------------------
extern "C" void kernel_launch(void* const* d_in, const int* in_sizes, int n_in,
                              void* d_out, int out_size, void* d_ws, size_t ws_size,
                              hipStream_t stream)
{
    const float* x    = (const float*)d_in[0];
    const float* wq   = (const float*)d_in[1];
    const float* bq   = (const float*)d_in[2];
    const float* bnq  = (const float*)d_in[3];
    const float* wk   = (const float*)d_in[4];
    const float* bk   = (const float*)d_in[5];
    const float* bnk  = (const float*)d_in[6];
    const float* wv   = (const float*)d_in[7];
    const float* bv   = (const float*)d_in[8];
    const float* bnv  = (const float*)d_in[9];
    const float* wvl  = (const float*)d_in[10];
    const float* bvl  = (const float*)d_in[11];
    const float* bnvl = (const float*)d_in[12];
    const float* th1w = (const float*)d_in[13];
    const float* th1b = (const float*)d_in[14];
    const float* th2w = (const float*)d_in[15];
    const float* th2b = (const float*)d_in[16];
    const float* wp   = (const float*)d_in[17];
    const float* bp   = (const float*)d_in[18];
    const float* bnp  = (const float*)d_in[19];
    const float* ab   = (const float*)d_in[20];
    const int*   bidx = (const int*)d_in[21];
    float* out = (float*)d_out;

    u16* wsb  = (u16*)d_ws;
    u16* WbI  = wsb + WBI_OFF;
    u16* WpI  = wsb + WPI_OFF;
    u16* qI   = wsb + QI_OFF;
    u16* kI   = wsb + KI_OFF;
    u16* vI   = wsb + VI_OFF;
    u16* PbI  = wsb + PBI_OFF;
    float* vloc = (float*)(wsb + VLOC_U16);
    u16* xI   = wsb + TAIL_OFF;   // aliased: xI -> Sh -> aoI (disjoint lifetimes)
    u16* Sh   = wsb + TAIL_OFF;
    u16* aoI  = wsb + TAIL_OFF;
    float* TB  = (float*)(wsb + TB_OFF);
    float* abT = (float*)(wsb + ABT_OFF);

    k_castW<<<dim3(3859), 256, 0, stream>>>(wq, wk, wv, wp, ab,
                                            bq, bnq, bk, bnk, bv, bnv, bp, bnp, bvl, bnvl,
                                            WbI, WpI, abT, TB);
    k_castX<<<dim3(4, 6, B_), 256, 0, stream>>>(x, xI);
    k_qkv<<<dim3(2, 12, B_), 256, 0, stream>>>(WbI, xI, TB, qI, kI, vI);
    k_dwconv<<<dim3((B_ * DH_ * N_ + 255) / 256), 256, 0, stream>>>(vI, wvl, TB, vloc);
    k_score<<<dim3(4, HEADS_, B_), 256, 0, stream>>>(qI, kI, Sh);
    k_soft<<<dim3(N_, B_), 256, 0, stream>>>(Sh, th1w, th1b, th2w, th2b, abT, bidx, PbI);
    k_av<<<dim3(2, HEADS_, B_), 256, 0, stream>>>(vI, PbI, vloc, aoI);
    k_proj<<<dim3(2, 3, B_), 256, 0, stream>>>(WpI, aoI, TB, out);
}

// Round 5
// 451.755 us; speedup vs baseline: 1.2192x; 1.0314x over previous
//
#include <hip/hip_runtime.h>

#define B_     64
#define DIM_   384
#define RES_   14
#define N_     196
#define HEADS_ 8
#define KD_    32
#define D_     128
#define DH_    1024
#define QK_    256
#define CH_    1536
#define EPS_   1e-5f
#define SCALE_ 0.17677669529663687f   // 32^-0.5

typedef unsigned short u16;
typedef short v8s __attribute__((ext_vector_type(8)));
typedef float v4f __attribute__((ext_vector_type(4)));
typedef u16  v4u __attribute__((ext_vector_type(4)));

static __device__ __forceinline__ u16 f2bf(float f) {
    unsigned int u = __builtin_bit_cast(unsigned int, f);
    u = (u + 0x7fffu + ((u >> 16) & 1u)) >> 16;
    return (u16)u;
}
static __device__ __forceinline__ float bf2f(u16 u) {
    unsigned int x = ((unsigned int)u) << 16;
    return __builtin_bit_cast(float, x);
}
static __device__ __forceinline__ u16 f2h(float f) {
    _Float16 h = (_Float16)f;
    return __builtin_bit_cast(u16, h);
}
static __device__ __forceinline__ float h2f(u16 u) {
    return (float)__builtin_bit_cast(_Float16, u);
}

// async global->LDS, 16B per lane; LDS dest = wave-uniform base + lane*16
static __device__ __forceinline__ void gload_lds16(const u16* g, u16* l) {
    __builtin_amdgcn_global_load_lds(
        (const __attribute__((address_space(1))) void*)g,
        (__attribute__((address_space(3))) void*)l, 16, 0, 0);
}

// workspace layout (u16 element offsets)
// GEMM operand images: [kstep][kquad(4)][row(128)][8] = 4096 elems (8KB)/kstep
#define WBI_OFF  0u          // Wb  image: 12 mtiles x 12 ksteps      (589824)
#define WPI_OFF  589824u     // wp  image: 3 mtiles x 32 ksteps       (393216)
#define QI_OFF   983040u     // qT  [B][8][256][32]                   (4194304)
#define KI_OFF   5177344u    // kT  [B][8][256][32]                   (4194304)
#define VI_OFF   9371648u    // v   image: [B][8] x 7 ksteps          (14680064)
#define PBI_OFF  24051712u   // P   image: [B][8][nt2] x 7 ksteps     (29360128)
#define VLOC_U16 53411840u   // vloc [B][1024][196] fp32              (25690112 u16)
#define TAIL_OFF 79101952u   // union: xI (6291456) / Sh fp16 (19668992) / aoI (16777216)
#define TB_OFF   98770944u   // BN tables fp32[5888]
#define ABT_OFF  98782720u   // abT [196][8] fp32

// ---------------------------------------------------------------------------
// 128x128 MFMA GEMM core, operands pre-packed as LDS images.
// ---------------------------------------------------------------------------
static __device__ __forceinline__ void gemm_core_g(
    const u16* __restrict__ Aimg, const u16* __restrict__ Bimg,
    int ksteps, u16* sA, u16* sB, v4f acc[4][4], int tid)
{
    const int lane = tid & 63;
    const int w    = tid >> 6;
    const int wm   = (w & 1) * 64;
    const int wn   = (w >> 1) * 64;
    const int quad = lane >> 4;
    const int l16  = lane & 15;
    const int la   = lane * 8;
    const int c0   = w * 1024;   // wave's two 512-elem chunks

    for (int ks = 0; ks < ksteps; ks++) {
        const u16* ga = Aimg + ks * 4096 + la;
        const u16* gb = Bimg + ks * 4096 + la;
        gload_lds16(ga + c0,       sA + c0);
        gload_lds16(ga + c0 + 512, sA + c0 + 512);
        gload_lds16(gb + c0,       sB + c0);
        gload_lds16(gb + c0 + 512, sB + c0 + 512);
        __syncthreads();
        v8s af[4], bf[4];
        #pragma unroll
        for (int i = 0; i < 4; i++)
            af[i] = *(const v8s*)&sA[(quad * 128 + wm + i * 16 + l16) * 8];
        #pragma unroll
        for (int j = 0; j < 4; j++)
            bf[j] = *(const v8s*)&sB[(quad * 128 + wn + j * 16 + l16) * 8];
        #pragma unroll
        for (int i = 0; i < 4; i++)
            #pragma unroll
            for (int j = 0; j < 4; j++)
                acc[i][j] = __builtin_amdgcn_mfma_f32_16x16x32_bf16(af[i], bf[j], acc[i][j], 0, 0, 0);
        __syncthreads();
    }
}

// ---------------------------------------------------------------------------
// pack weights into tile images + abT + BN scale/shift tables
// ---------------------------------------------------------------------------
__global__ __launch_bounds__(256) void k_castW(
    const float* __restrict__ wq, const float* __restrict__ wk,
    const float* __restrict__ wv, const float* __restrict__ wp,
    const float* __restrict__ ab,
    const float* __restrict__ bq, const float* __restrict__ bnq,
    const float* __restrict__ bk, const float* __restrict__ bnk,
    const float* __restrict__ bv, const float* __restrict__ bnv,
    const float* __restrict__ bp, const float* __restrict__ bnp,
    const float* __restrict__ bvl, const float* __restrict__ bnvl,
    u16* __restrict__ WbI, u16* __restrict__ WpI,
    float* __restrict__ abT, float* __restrict__ TB)
{
    int i = blockIdx.x * 256 + threadIdx.x;
    if (i < 589824) {           // qkv weight image
        int mt = i / 49152, rem = i % 49152;
        int ks = rem >> 12, r2 = rem & 4095;
        int q = r2 >> 10, row = (r2 >> 3) & 127, e = r2 & 7;
        int c = mt * 128 + row, k = ks * 32 + q * 8 + e;
        float v = (c < 256) ? wq[c * 384 + k]
                : (c < 512) ? wk[(c - 256) * 384 + k]
                            : wv[(size_t)(c - 512) * 384 + k];
        WbI[i] = f2bf(v);
    } else if (i < 983040) {    // proj weight image
        int j = i - 589824;
        int mt = j >> 17, rem = j & 131071;
        int ks = rem >> 12, r2 = rem & 4095;
        int q = r2 >> 10, row = (r2 >> 3) & 127, e = r2 & 7;
        int p = mt * 128 + row, k = ks * 32 + q * 8 + e;
        WpI[j] = f2bf(wp[(size_t)p * 1024 + k]);
    } else if (i < 984608) {    // abT
        int j = i - 983040;
        abT[j] = ab[(j & 7) * N_ + (j >> 3)];
    } else if (i < 987552) {    // BN tables
        int j = i - 984608;
        if (j < 256) {
            int c = j;
            float s = bnq[c] * rsqrtf(bnq[768 + c] + EPS_);
            float t = (bq[c] - bnq[512 + c]) * s + bnq[256 + c];
            TB[c] = s * SCALE_; TB[256 + c] = t * SCALE_;
        } else if (j < 512) {
            int c = j - 256;
            float s = bnk[c] * rsqrtf(bnk[768 + c] + EPS_);
            float t = (bk[c] - bnk[512 + c]) * s + bnk[256 + c];
            TB[512 + c] = s; TB[768 + c] = t;
        } else if (j < 1536) {
            int c = j - 512;
            float s = bnv[c] * rsqrtf(bnv[3072 + c] + EPS_);
            float t = (bv[c] - bnv[2048 + c]) * s + bnv[1024 + c];
            TB[1024 + c] = s; TB[2048 + c] = t;
        } else if (j < 1920) {
            int c = j - 1536;
            float s = bnp[c] * rsqrtf(bnp[1152 + c] + EPS_);
            float t = (bp[c] - bnp[768 + c]) * s + bnp[384 + c];
            TB[3072 + c] = s; TB[3456 + c] = t;
        } else {
            int c = j - 1920;
            float s = bnvl[c] * rsqrtf(bnvl[3072 + c] + EPS_);
            float t = (bvl[c] - bnvl[2048 + c]) * s + bnvl[1024 + c];
            TB[3840 + c] = s; TB[4864 + c] = t;
        }
    }
}

// ---------------------------------------------------------------------------
// x [B,384,196] fp32 -> xI image [B][nt2][12 ksteps][4096] bf16 (n>=196 zero)
// ---------------------------------------------------------------------------
__global__ __launch_bounds__(256) void k_castX(
    const float* __restrict__ x, u16* __restrict__ xI)
{
    __shared__ float T[64][65];
    const int tid = threadIdx.x;
    const int n0 = blockIdx.x * 64;
    const int k0 = blockIdx.y * 64;
    const int b  = blockIdx.z;
    const int c = tid & 63, r4 = tid >> 6;
    #pragma unroll
    for (int i = 0; i < 16; i++) {
        int kr = i * 4 + r4;
        int gn = n0 + c;
        T[kr][c] = (gn < N_) ? x[((size_t)b * DIM_ + k0 + kr) * N_ + gn] : 0.f;
    }
    __syncthreads();
    #pragma unroll
    for (int it = 0; it < 16; it++) {
        int j = it * 256 + tid;
        int kk = j & 63, nn = j >> 6;
        int k = k0 + kk, n = n0 + nn;
        xI[(size_t)b * 98304 + (n >> 7) * 49152 + (k >> 5) * 4096
           + ((k >> 3) & 3) * 1024 + (n & 127) * 8 + (k & 7)] = f2bf(T[kk][nn]);
    }
}

// ---------------------------------------------------------------------------
// K1: QKV GEMM. Outputs: qI/kI [b][h][256][32] bf16 (q pre-scaled),
// vI image per (b,o), 7 ksteps (n>=196 zero).
// ---------------------------------------------------------------------------
__global__ __launch_bounds__(256) void k_qkv(
    const u16* __restrict__ WbI, const u16* __restrict__ xI,
    const float* __restrict__ TB,
    u16* __restrict__ qI, u16* __restrict__ kI, u16* __restrict__ vI)
{
    __shared__ u16 sA[4096];
    __shared__ u16 sB[4096];
    const int tid = threadIdx.x;
    const int nt = blockIdx.x;
    const int mt = blockIdx.y;
    const int b  = blockIdx.z;
    v4f acc[4][4] = {};
    gemm_core_g(WbI + (size_t)mt * 49152,
                xI + ((size_t)b * 2 + nt) * 49152, 12, sA, sB, acc, tid);

    const int lane = tid & 63, w = tid >> 6;
    const int wm = (w & 1) * 64, wn = (w >> 1) * 64;
    const int quad = lane >> 4, l16 = lane & 15;
    #pragma unroll
    for (int i = 0; i < 4; i++) {
        #pragma unroll
        for (int j = 0; j < 4; j++) {
            int gc = mt * 128 + wm + i * 16 + quad * 4;  // global channel base
            int n  = nt * 128 + wn + j * 16 + l16;       // token (0..255)
            v4f v = acc[i][j];
            if (gc < 256) {            // q
                v4f s = *(const v4f*)&TB[gc];
                v4f t = *(const v4f*)&TB[256 + gc];
                v4u u;
                #pragma unroll
                for (int r = 0; r < 4; r++) u[r] = f2bf(v[r] * s[r] + t[r]);
                *(v4u*)&qI[((size_t)(b * 8 + (gc >> 5)) * 256 + n) * 32 + (gc & 31)] = u;
            } else if (gc < 512) {     // k
                int c = gc - 256;
                v4f s = *(const v4f*)&TB[512 + c];
                v4f t = *(const v4f*)&TB[768 + c];
                v4u u;
                #pragma unroll
                for (int r = 0; r < 4; r++) u[r] = f2bf(v[r] * s[r] + t[r]);
                *(v4u*)&kI[((size_t)(b * 8 + (c >> 5)) * 256 + n) * 32 + (c & 31)] = u;
            } else {                   // v -> image (row = e, col = n as k-dim)
                int c = gc - 512;      // 0..1023
                if (n < 224) {
                    int o = c >> 7, e = c & 127;
                    u16* base = vI + ((size_t)(b * 8 + o) * 7 + (n >> 5)) * 4096
                                + ((n >> 3) & 3) * 1024 + (n & 7);
                    #pragma unroll
                    for (int r = 0; r < 4; r++) {
                        u16 outv = 0;
                        if (n < N_) outv = f2bf(v[r] * TB[1024 + c + r] + TB[2048 + c + r]);
                        base[(e + r) * 8] = outv;
                    }
                }
            }
        }
    }
}

// ---------------------------------------------------------------------------
// K2: depthwise 3x3 conv. Block = (b,o): stage the full 128-channel image in
// LDS (coalesced 1KB/wave loads, decoded to plain [e][224]), then 9-tap from
// LDS with stride-1 lane access. 512 blocks = 2/CU.
// ---------------------------------------------------------------------------
__global__ __launch_bounds__(256) void k_dwconv(
    const u16* __restrict__ vI, const float* __restrict__ wvl,
    const float* __restrict__ TB, float* __restrict__ vloc)
{
    __shared__ u16 V[128 * 224];   // 57344 B
    const int tid = threadIdx.x;
    const int o = blockIdx.x & 7;
    const int b = blockIdx.x >> 3;
    const u16* img = vI + (size_t)(b * 8 + o) * 28672;

    #pragma unroll
    for (int i = 0; i < 14; i++) {
        int t = i * 256 + tid;               // 8-elem group index
        v8s u = *(const v8s*)&img[t * 8];
        int e  = t & 127;
        int mb = (t >> 9) * 32 + ((t >> 7) & 3) * 8;
        *(v8s*)&V[e * 224 + mb] = u;
    }
    __syncthreads();

    const int c0 = o * 128;
    int e = tid / 196, n = tid - e * 196;    // j = e*196+n walk, j += 256
    #pragma unroll 2
    for (int i = 0; i < 98; i++) {
        int c = c0 + e;
        int y = n / 14, x0 = n - y * 14;
        const float* wgt = wvl + c * 9;
        const u16* row = &V[e * 224];
        float s = 0.f;
        #pragma unroll
        for (int ky = 0; ky < 3; ky++) {
            int yy = y + ky - 1;
            if (yy < 0 || yy >= RES_) continue;
            #pragma unroll
            for (int kx = 0; kx < 3; kx++) {
                int xx = x0 + kx - 1;
                if (xx < 0 || xx >= RES_) continue;
                s += bf2f(row[yy * RES_ + xx]) * wgt[ky * 3 + kx];
            }
        }
        vloc[((size_t)b * DH_ + c) * N_ + n] = s * TB[3840 + c] + TB[4864 + c];
        // advance flat index by 256: 256 = 196 + 60
        n += 60; e += 1;
        if (n >= 196) { n -= 196; e += 1; }
    }
}

// ---------------------------------------------------------------------------
// K3: score GEMM per (b,h), LDS-free; qI/kI rows are MFMA fragments
// ---------------------------------------------------------------------------
__global__ __launch_bounds__(256) void k_score(
    const u16* __restrict__ qI, const u16* __restrict__ kI,
    u16* __restrict__ Sh)
{
    const int tid = threadIdx.x;
    const int w = tid >> 6, lane = tid & 63;
    const int quad = lane >> 4, l16 = lane & 15;
    const int b = blockIdx.z, h = blockIdx.y;
    const int qt = blockIdx.x * 4 + w;
    if (qt >= 13) return;   // wave-uniform

    const u16* qb = qI + (size_t)(b * 8 + h) * 8192;
    const u16* kb = kI + (size_t)(b * 8 + h) * 8192;
    v8s a = *(const v8s*)&qb[(qt * 16 + l16) * 32 + quad * 8];
    const int q0 = qt * 16 + quad * 4;
    u16* So = Sh + (size_t)(b * 8 + h) * N_ * N_;

    for (int mt = 0; mt < 13; mt++) {
        v8s bfr = *(const v8s*)&kb[(mt * 16 + l16) * 32 + quad * 8];
        v4f acc = {};
        acc = __builtin_amdgcn_mfma_f32_16x16x32_bf16(a, bfr, acc, 0, 0, 0);
        int m = mt * 16 + l16;
        if (m < N_) {
            #pragma unroll
            for (int r = 0; r < 4; r++) {
                int q = q0 + r;
                if (q < N_) So[(size_t)q * N_ + m] = f2h(acc[r]);
            }
        }
    }
}

// ---------------------------------------------------------------------------
// K4: register-resident softmax/talking-heads -> P image
// ---------------------------------------------------------------------------
__global__ __launch_bounds__(256) void k_soft(
    const u16* __restrict__ Sh,
    const float* __restrict__ th1w, const float* __restrict__ th1b,
    const float* __restrict__ th2w, const float* __restrict__ th2b,
    const float* __restrict__ abT, const int* __restrict__ bidx,
    u16* __restrict__ PbI)
{
    __shared__ float red[2][4][8];
    const int tid = threadIdx.x;
    const int m = tid;
    const int w = tid >> 6;
    const int n = blockIdx.x, b = blockIdx.y;
    const bool act = (m < N_);

    float S[8];
    if (act) {
        int idx = bidx[n * N_ + m];
        v4f ab0 = *(const v4f*)&abT[idx * 8];
        v4f ab1 = *(const v4f*)&abT[idx * 8 + 4];
        #pragma unroll
        for (int h = 0; h < 8; h++) {
            float bias = (h < 4) ? ab0[h] : ab1[h - 4];
            S[h] = h2f(Sh[((size_t)(b * 8 + h) * N_ + n) * N_ + m]) + bias;
        }
    } else {
        #pragma unroll
        for (int h = 0; h < 8; h++) S[h] = 0.f;
    }

    float A[8];
    #pragma unroll
    for (int o = 0; o < 8; o++) {
        float a = th1b[o];
        #pragma unroll
        for (int h = 0; h < 8; h++) a += th1w[o * 8 + h] * S[h];
        A[o] = act ? a : -1e30f;
    }

    #pragma unroll
    for (int o = 0; o < 8; o++) {
        float v = A[o];
        #pragma unroll
        for (int off = 32; off > 0; off >>= 1) v = fmaxf(v, __shfl_xor(v, off, 64));
        if ((tid & 63) == 0) red[0][w][o] = v;
    }
    __syncthreads();
    float e[8];
    #pragma unroll
    for (int o = 0; o < 8; o++) {
        float mx = fmaxf(fmaxf(red[0][0][o], red[0][1][o]),
                         fmaxf(red[0][2][o], red[0][3][o]));
        e[o] = act ? __expf(A[o] - mx) : 0.f;
    }
    #pragma unroll
    for (int o = 0; o < 8; o++) {
        float v = e[o];
        #pragma unroll
        for (int off = 32; off > 0; off >>= 1) v += __shfl_xor(v, off, 64);
        if ((tid & 63) == 0) red[1][w][o] = v;
    }
    __syncthreads();
    #pragma unroll
    for (int o = 0; o < 8; o++) {
        float sm = (red[1][0][o] + red[1][1][o]) + (red[1][2][o] + red[1][3][o]);
        e[o] *= (1.f / sm);
    }
    if (m < 224) {
        size_t rowoff = ((size_t)(m >> 5)) * 4096 + ((m >> 3) & 3) * 1024 + (n & 127) * 8 + (m & 7);
        #pragma unroll
        for (int o = 0; o < 8; o++) {
            float p = th2b[o];
            #pragma unroll
            for (int h = 0; h < 8; h++) p += th2w[o * 8 + h] * e[h];
            PbI[((size_t)(b * 8 + o) * 2 + (n >> 7)) * 28672 + rowoff] = act ? f2bf(p) : (u16)0;
        }
    }
}

// ---------------------------------------------------------------------------
// K5: attn @ V (K=224, 7 ksteps) + v_local + relu -> aoI image
// ---------------------------------------------------------------------------
__global__ __launch_bounds__(256) void k_av(
    const u16* __restrict__ vI, const u16* __restrict__ PbI,
    const float* __restrict__ vloc, u16* __restrict__ aoI)
{
    __shared__ u16 sA[4096];
    __shared__ u16 sB[4096];
    const int tid = threadIdx.x;
    const int nt = blockIdx.x;
    const int o  = blockIdx.y;
    const int b  = blockIdx.z;
    v4f acc[4][4] = {};
    gemm_core_g(vI + (size_t)(b * 8 + o) * 28672,
                PbI + ((size_t)(b * 8 + o) * 2 + nt) * 28672, 7, sA, sB, acc, tid);

    const int lane = tid & 63, w = tid >> 6;
    const int wm = (w & 1) * 64, wn = (w >> 1) * 64;
    const int quad = lane >> 4, l16 = lane & 15;
    #pragma unroll
    for (int i = 0; i < 4; i++) {
        #pragma unroll
        for (int j = 0; j < 4; j++) {
            int lr = wm + i * 16 + quad * 4;        // e base
            int c0 = o * 128 + lr;                  // global k-index base
            int n  = nt * 128 + wn + j * 16 + l16;  // token (0..255)
            v4u u;
            #pragma unroll
            for (int r = 0; r < 4; r++) {
                u16 outv = 0;
                if (n < N_) {
                    float val = acc[i][j][r] + vloc[((size_t)b * DH_ + c0 + r) * N_ + n];
                    outv = f2bf(fmaxf(val, 0.f));
                }
                u[r] = outv;
            }
            *(v4u*)&aoI[((size_t)(b * 2 + nt) * 32 + (c0 >> 5)) * 4096
                        + ((c0 >> 3) & 3) * 1024 + (n & 127) * 8 + (c0 & 7)] = u;
        }
    }
}

// ---------------------------------------------------------------------------
// K6: projection GEMM (K=1024, 32 ksteps) + BN -> out fp32
// ---------------------------------------------------------------------------
__global__ __launch_bounds__(256) void k_proj(
    const u16* __restrict__ WpI, const u16* __restrict__ aoI,
    const float* __restrict__ TB, float* __restrict__ out)
{
    __shared__ u16 sA[4096];
    __shared__ u16 sB[4096];
    const int tid = threadIdx.x;
    const int nt = blockIdx.x;
    const int mt = blockIdx.y;
    const int b  = blockIdx.z;
    v4f acc[4][4] = {};
    gemm_core_g(WpI + (size_t)mt * 131072,
                aoI + (size_t)(b * 2 + nt) * 131072, 32, sA, sB, acc, tid);

    const int lane = tid & 63, w = tid >> 6;
    const int wm = (w & 1) * 64, wn = (w >> 1) * 64;
    const int quad = lane >> 4, l16 = lane & 15;
    #pragma unroll
    for (int i = 0; i < 4; i++) {
        #pragma unroll
        for (int j = 0; j < 4; j++) {
            int p0 = mt * 128 + wm + i * 16 + quad * 4;
            int n  = nt * 128 + wn + j * 16 + l16;
            if (n < N_) {
                v4f s = *(const v4f*)&TB[3072 + p0];
                v4f t = *(const v4f*)&TB[3456 + p0];
                #pragma unroll
                for (int r = 0; r < 4; r++)
                    out[((size_t)b * DIM_ + p0 + r) * N_ + n] = acc[i][j][r] * s[r] + t[r];
            }
        }
    }
}

// ---------------------------------------------------------------------------
extern "C" void kernel_launch(void* const* d_in, const int* in_sizes, int n_in,
                              void* d_out, int out_size, void* d_ws, size_t ws_size,
                              hipStream_t stream)
{
    const float* x    = (const float*)d_in[0];
    const float* wq   = (const float*)d_in[1];
    const float* bq   = (const float*)d_in[2];
    const float* bnq  = (const float*)d_in[3];
    const float* wk   = (const float*)d_in[4];
    const float* bk   = (const float*)d_in[5];
    const float* bnk  = (const float*)d_in[6];
    const float* wv   = (const float*)d_in[7];
    const float* bv   = (const float*)d_in[8];
    const float* bnv  = (const float*)d_in[9];
    const float* wvl  = (const float*)d_in[10];
    const float* bvl  = (const float*)d_in[11];
    const float* bnvl = (const float*)d_in[12];
    const float* th1w = (const float*)d_in[13];
    const float* th1b = (const float*)d_in[14];
    const float* th2w = (const float*)d_in[15];
    const float* th2b = (const float*)d_in[16];
    const float* wp   = (const float*)d_in[17];
    const float* bp   = (const float*)d_in[18];
    const float* bnp  = (const float*)d_in[19];
    const float* ab   = (const float*)d_in[20];
    const int*   bidx = (const int*)d_in[21];
    float* out = (float*)d_out;

    u16* wsb  = (u16*)d_ws;
    u16* WbI  = wsb + WBI_OFF;
    u16* WpI  = wsb + WPI_OFF;
    u16* qI   = wsb + QI_OFF;
    u16* kI   = wsb + KI_OFF;
    u16* vI   = wsb + VI_OFF;
    u16* PbI  = wsb + PBI_OFF;
    float* vloc = (float*)(wsb + VLOC_U16);
    u16* xI   = wsb + TAIL_OFF;   // aliased: xI -> Sh -> aoI (disjoint lifetimes)
    u16* Sh   = wsb + TAIL_OFF;
    u16* aoI  = wsb + TAIL_OFF;
    float* TB  = (float*)(wsb + TB_OFF);
    float* abT = (float*)(wsb + ABT_OFF);

    k_castW<<<dim3(3859), 256, 0, stream>>>(wq, wk, wv, wp, ab,
                                            bq, bnq, bk, bnk, bv, bnv, bp, bnp, bvl, bnvl,
                                            WbI, WpI, abT, TB);
    k_castX<<<dim3(4, 6, B_), 256, 0, stream>>>(x, xI);
    k_qkv<<<dim3(2, 12, B_), 256, 0, stream>>>(WbI, xI, TB, qI, kI, vI);
    k_dwconv<<<dim3(B_ * 8), 256, 0, stream>>>(vI, wvl, TB, vloc);
    k_score<<<dim3(4, HEADS_, B_), 256, 0, stream>>>(qI, kI, Sh);
    k_soft<<<dim3(N_, B_), 256, 0, stream>>>(Sh, th1w, th1b, th2w, th2b, abT, bidx, PbI);
    k_av<<<dim3(2, HEADS_, B_), 256, 0, stream>>>(vI, PbI, vloc, aoI);
    k_proj<<<dim3(2, 3, B_), 256, 0, stream>>>(WpI, aoI, TB, out);
}

// Round 6
// 364.206 us; speedup vs baseline: 1.5122x; 1.2404x over previous
//
#include <hip/hip_runtime.h>

#define B_     64
#define DIM_   384
#define RES_   14
#define N_     196
#define HEADS_ 8
#define KD_    32
#define D_     128
#define DH_    1024
#define QK_    256
#define CH_    1536
#define EPS_   1e-5f
#define SCALE_ 0.17677669529663687f   // 32^-0.5

typedef unsigned short u16;
typedef unsigned int u32;
typedef short v8s __attribute__((ext_vector_type(8)));
typedef float v4f __attribute__((ext_vector_type(4)));
typedef u16  v4u __attribute__((ext_vector_type(4)));

static __device__ __forceinline__ u16 f2bf(float f) {
    unsigned int u = __builtin_bit_cast(unsigned int, f);
    u = (u + 0x7fffu + ((u >> 16) & 1u)) >> 16;
    return (u16)u;
}
static __device__ __forceinline__ float bf2f(u16 u) {
    unsigned int x = ((unsigned int)u) << 16;
    return __builtin_bit_cast(float, x);
}
static __device__ __forceinline__ u16 f2h(float f) {
    _Float16 h = (_Float16)f;
    return __builtin_bit_cast(u16, h);
}
static __device__ __forceinline__ float h2f(u16 u) {
    return (float)__builtin_bit_cast(_Float16, u);
}

// async global->LDS, 16B per lane; LDS dest = wave-uniform base + lane*16
static __device__ __forceinline__ void gload_lds16(const u16* g, u16* l) {
    __builtin_amdgcn_global_load_lds(
        (const __attribute__((address_space(1))) void*)g,
        (__attribute__((address_space(3))) void*)l, 16, 0, 0);
}

// workspace layout (u16 element offsets)
// GEMM operand images: [kstep][kquad(4)][row(128)][8] = 4096 elems (8KB)/kstep
#define WBI_OFF  0u          // Wb  image: 12 mtiles x 12 ksteps      (589824)
#define WPI_OFF  589824u     // wp  image: 3 mtiles x 32 ksteps       (393216)
#define QI_OFF   983040u     // qT  [B][8][256][32]                   (4194304)
#define KI_OFF   5177344u    // kT  [B][8][256][32]                   (4194304)
#define VI_OFF   9371648u    // v   image: [B][8] x 7 ksteps          (14680064)
#define PBI_OFF  24051712u   // P   image: [B][8][nt2] x 7 ksteps     (29360128)
#define VLOC_U16 53411840u   // vloc [B][1024][196] bf16              (12845056 u16)
#define TAIL_OFF 79101952u   // union: xI (6291456) / Sh fp16 (19668992) / aoI (16777216)
#define TB_OFF   98770944u   // BN tables fp32[5888]
#define ABT_OFF  98782720u   // abT [196][8] fp32

// ---------------------------------------------------------------------------
// 128x128 MFMA GEMM core, operands pre-packed as LDS images.
// ---------------------------------------------------------------------------
static __device__ __forceinline__ void gemm_core_g(
    const u16* __restrict__ Aimg, const u16* __restrict__ Bimg,
    int ksteps, u16* sA, u16* sB, v4f acc[4][4], int tid)
{
    const int lane = tid & 63;
    const int w    = tid >> 6;
    const int wm   = (w & 1) * 64;
    const int wn   = (w >> 1) * 64;
    const int quad = lane >> 4;
    const int l16  = lane & 15;
    const int la   = lane * 8;
    const int c0   = w * 1024;   // wave's two 512-elem chunks

    for (int ks = 0; ks < ksteps; ks++) {
        const u16* ga = Aimg + ks * 4096 + la;
        const u16* gb = Bimg + ks * 4096 + la;
        gload_lds16(ga + c0,       sA + c0);
        gload_lds16(ga + c0 + 512, sA + c0 + 512);
        gload_lds16(gb + c0,       sB + c0);
        gload_lds16(gb + c0 + 512, sB + c0 + 512);
        __syncthreads();
        v8s af[4], bf[4];
        #pragma unroll
        for (int i = 0; i < 4; i++)
            af[i] = *(const v8s*)&sA[(quad * 128 + wm + i * 16 + l16) * 8];
        #pragma unroll
        for (int j = 0; j < 4; j++)
            bf[j] = *(const v8s*)&sB[(quad * 128 + wn + j * 16 + l16) * 8];
        #pragma unroll
        for (int i = 0; i < 4; i++)
            #pragma unroll
            for (int j = 0; j < 4; j++)
                acc[i][j] = __builtin_amdgcn_mfma_f32_16x16x32_bf16(af[i], bf[j], acc[i][j], 0, 0, 0);
        __syncthreads();
    }
}

// ---------------------------------------------------------------------------
// pack weights into tile images + abT + BN scale/shift tables
// ---------------------------------------------------------------------------
__global__ __launch_bounds__(256) void k_castW(
    const float* __restrict__ wq, const float* __restrict__ wk,
    const float* __restrict__ wv, const float* __restrict__ wp,
    const float* __restrict__ ab,
    const float* __restrict__ bq, const float* __restrict__ bnq,
    const float* __restrict__ bk, const float* __restrict__ bnk,
    const float* __restrict__ bv, const float* __restrict__ bnv,
    const float* __restrict__ bp, const float* __restrict__ bnp,
    const float* __restrict__ bvl, const float* __restrict__ bnvl,
    u16* __restrict__ WbI, u16* __restrict__ WpI,
    float* __restrict__ abT, float* __restrict__ TB)
{
    int i = blockIdx.x * 256 + threadIdx.x;
    if (i < 589824) {           // qkv weight image
        int mt = i / 49152, rem = i % 49152;
        int ks = rem >> 12, r2 = rem & 4095;
        int q = r2 >> 10, row = (r2 >> 3) & 127, e = r2 & 7;
        int c = mt * 128 + row, k = ks * 32 + q * 8 + e;
        float v = (c < 256) ? wq[c * 384 + k]
                : (c < 512) ? wk[(c - 256) * 384 + k]
                            : wv[(size_t)(c - 512) * 384 + k];
        WbI[i] = f2bf(v);
    } else if (i < 983040) {    // proj weight image
        int j = i - 589824;
        int mt = j >> 17, rem = j & 131071;
        int ks = rem >> 12, r2 = rem & 4095;
        int q = r2 >> 10, row = (r2 >> 3) & 127, e = r2 & 7;
        int p = mt * 128 + row, k = ks * 32 + q * 8 + e;
        WpI[j] = f2bf(wp[(size_t)p * 1024 + k]);
    } else if (i < 984608) {    // abT
        int j = i - 983040;
        abT[j] = ab[(j & 7) * N_ + (j >> 3)];
    } else if (i < 987552) {    // BN tables
        int j = i - 984608;
        if (j < 256) {
            int c = j;
            float s = bnq[c] * rsqrtf(bnq[768 + c] + EPS_);
            float t = (bq[c] - bnq[512 + c]) * s + bnq[256 + c];
            TB[c] = s * SCALE_; TB[256 + c] = t * SCALE_;
        } else if (j < 512) {
            int c = j - 256;
            float s = bnk[c] * rsqrtf(bnk[768 + c] + EPS_);
            float t = (bk[c] - bnk[512 + c]) * s + bnk[256 + c];
            TB[512 + c] = s; TB[768 + c] = t;
        } else if (j < 1536) {
            int c = j - 512;
            float s = bnv[c] * rsqrtf(bnv[3072 + c] + EPS_);
            float t = (bv[c] - bnv[2048 + c]) * s + bnv[1024 + c];
            TB[1024 + c] = s; TB[2048 + c] = t;
        } else if (j < 1920) {
            int c = j - 1536;
            float s = bnp[c] * rsqrtf(bnp[1152 + c] + EPS_);
            float t = (bp[c] - bnp[768 + c]) * s + bnp[384 + c];
            TB[3072 + c] = s; TB[3456 + c] = t;
        } else {
            int c = j - 1920;
            float s = bnvl[c] * rsqrtf(bnvl[3072 + c] + EPS_);
            float t = (bvl[c] - bnvl[2048 + c]) * s + bnvl[1024 + c];
            TB[3840 + c] = s; TB[4864 + c] = t;
        }
    }
}

// ---------------------------------------------------------------------------
// x [B,384,196] fp32 -> xI image [B][nt2][12 ksteps][4096] bf16 (n>=196 zero)
// ---------------------------------------------------------------------------
__global__ __launch_bounds__(256) void k_castX(
    const float* __restrict__ x, u16* __restrict__ xI)
{
    __shared__ float T[64][65];
    const int tid = threadIdx.x;
    const int n0 = blockIdx.x * 64;
    const int k0 = blockIdx.y * 64;
    const int b  = blockIdx.z;
    const int c = tid & 63, r4 = tid >> 6;
    #pragma unroll
    for (int i = 0; i < 16; i++) {
        int kr = i * 4 + r4;
        int gn = n0 + c;
        T[kr][c] = (gn < N_) ? x[((size_t)b * DIM_ + k0 + kr) * N_ + gn] : 0.f;
    }
    __syncthreads();
    #pragma unroll
    for (int it = 0; it < 16; it++) {
        int j = it * 256 + tid;
        int kk = j & 63, nn = j >> 6;
        int k = k0 + kk, n = n0 + nn;
        xI[(size_t)b * 98304 + (n >> 7) * 49152 + (k >> 5) * 4096
           + ((k >> 3) & 3) * 1024 + (n & 127) * 8 + (k & 7)] = f2bf(T[kk][nn]);
    }
}

// ---------------------------------------------------------------------------
// K1: QKV GEMM. Outputs: qI/kI [b][h][256][32] bf16 (q pre-scaled),
// vI image per (b,o), 7 ksteps (n>=196 zero).
// ---------------------------------------------------------------------------
__global__ __launch_bounds__(256) void k_qkv(
    const u16* __restrict__ WbI, const u16* __restrict__ xI,
    const float* __restrict__ TB,
    u16* __restrict__ qI, u16* __restrict__ kI, u16* __restrict__ vI)
{
    __shared__ u16 sA[4096];
    __shared__ u16 sB[4096];
    const int tid = threadIdx.x;
    const int nt = blockIdx.x;
    const int mt = blockIdx.y;
    const int b  = blockIdx.z;
    v4f acc[4][4] = {};
    gemm_core_g(WbI + (size_t)mt * 49152,
                xI + ((size_t)b * 2 + nt) * 49152, 12, sA, sB, acc, tid);

    const int lane = tid & 63, w = tid >> 6;
    const int wm = (w & 1) * 64, wn = (w >> 1) * 64;
    const int quad = lane >> 4, l16 = lane & 15;
    #pragma unroll
    for (int i = 0; i < 4; i++) {
        #pragma unroll
        for (int j = 0; j < 4; j++) {
            int gc = mt * 128 + wm + i * 16 + quad * 4;  // global channel base
            int n  = nt * 128 + wn + j * 16 + l16;       // token (0..255)
            v4f v = acc[i][j];
            if (gc < 256) {            // q
                v4f s = *(const v4f*)&TB[gc];
                v4f t = *(const v4f*)&TB[256 + gc];
                v4u u;
                #pragma unroll
                for (int r = 0; r < 4; r++) u[r] = f2bf(v[r] * s[r] + t[r]);
                *(v4u*)&qI[((size_t)(b * 8 + (gc >> 5)) * 256 + n) * 32 + (gc & 31)] = u;
            } else if (gc < 512) {     // k
                int c = gc - 256;
                v4f s = *(const v4f*)&TB[512 + c];
                v4f t = *(const v4f*)&TB[768 + c];
                v4u u;
                #pragma unroll
                for (int r = 0; r < 4; r++) u[r] = f2bf(v[r] * s[r] + t[r]);
                *(v4u*)&kI[((size_t)(b * 8 + (c >> 5)) * 256 + n) * 32 + (c & 31)] = u;
            } else {                   // v -> image (row = e, col = n as k-dim)
                int c = gc - 512;      // 0..1023
                if (n < 224) {
                    int o = c >> 7, e = c & 127;
                    u16* base = vI + ((size_t)(b * 8 + o) * 7 + (n >> 5)) * 4096
                                + ((n >> 3) & 3) * 1024 + (n & 7);
                    #pragma unroll
                    for (int r = 0; r < 4; r++) {
                        u16 outv = 0;
                        if (n < N_) outv = f2bf(v[r] * TB[1024 + c + r] + TB[2048 + c + r]);
                        base[(e + r) * 8] = outv;
                    }
                }
            }
        }
    }
}

// ---------------------------------------------------------------------------
// K2: depthwise 3x3 conv. Block = 64 channels of one (b,o):
// phase1 coalesced image load -> LDS rows V[e][230] (conflict-free stride);
// phase2 thread=(e, 4-row strip), vectorized u32 LDS reads;
// phase3 results through LDS -> coalesced 16B bf16 stores.
// ---------------------------------------------------------------------------
__global__ __launch_bounds__(256) void k_dwconv(
    const u16* __restrict__ vI, const float* __restrict__ wvl,
    const float* __restrict__ TB, u16* __restrict__ vlocB)
{
    __shared__ u16 V[64 * 230];             // 29440 B
    const int tid = threadIdx.x;
    const int sub = blockIdx.x;             // 0..15: o = sub>>1, half = sub&1
    const int b   = blockIdx.y;
    const int o   = sub >> 1;
    const int e0  = (sub & 1) * 64;
    const u16* img = vI + (size_t)(b * 8 + o) * 28672;

    // phase 1: load 64 rows (e0..e0+63), all m, coalesced 1KB/wave
    {
        const int quad = tid >> 6, l = tid & 63;
        #pragma unroll
        for (int i = 0; i < 7; i++) {
            v8s u = *(const v8s*)&img[i * 4096 + quad * 1024 + (e0 + l) * 8];
            const u32* ui = (const u32*)&u;
            int m0 = i * 32 + quad * 8;
            u32* dst = (u32*)&V[l * 230 + m0];
            #pragma unroll
            for (int c = 0; c < 4; c++) dst[c] = ui[c];
        }
    }
    __syncthreads();

    // phase 2: thread = (e = tid&63, j = tid>>6); rows 4j..4j+3 (j=3: 12,13)
    const int e = tid & 63, j = tid >> 6;
    const int cg = sub * 64 + e;            // channel within [0,1024)
    const int y0 = j * 4;
    const int ny = (j == 3) ? 2 : 4;
    float wgt[9];
    #pragma unroll
    for (int k = 0; k < 9; k++) wgt[k] = wvl[cg * 9 + k];
    const float sc = TB[3840 + cg], sh = TB[4864 + cg];
    u32 po[4][7];

    for (int yi = 0; yi < ny; yi++) {
        int y = y0 + yi;
        float a[3][16];
        #pragma unroll
        for (int dy = 0; dy < 3; dy++) {
            int yy = y + dy - 1;
            a[dy][0] = 0.f; a[dy][15] = 0.f;
            if (yy < 0 || yy > 13) {
                #pragma unroll
                for (int x = 1; x < 15; x++) a[dy][x] = 0.f;
            } else {
                const u16* rp = &V[e * 230 + yy * 14];
                #pragma unroll
                for (int c4 = 0; c4 < 7; c4++) {
                    u32 u = *(const u32*)&rp[c4 * 2];
                    a[dy][1 + 2 * c4] = bf2f((u16)(u & 0xffffu));
                    a[dy][2 + 2 * c4] = bf2f((u16)(u >> 16));
                }
            }
        }
        #pragma unroll
        for (int xp = 0; xp < 7; xp++) {
            u32 pk = 0;
            #pragma unroll
            for (int half = 0; half < 2; half++) {
                int x = 2 * xp + half;
                float s = 0.f;
                #pragma unroll
                for (int dy = 0; dy < 3; dy++)
                    #pragma unroll
                    for (int kx = 0; kx < 3; kx++)
                        s += wgt[dy * 3 + kx] * a[dy][x + kx];
                u16 bv = f2bf(s * sc + sh);
                pk |= ((u32)bv) << (16 * half);
            }
            po[yi][xp] = pk;
        }
    }
    __syncthreads();   // all V reads done

    // phase 3a: stash results flat O[e*196 + n] (reuse V buffer)
    for (int yi = 0; yi < ny; yi++) {
        u32* dst = (u32*)&V[e * 196 + (y0 + yi) * 14];
        #pragma unroll
        for (int xp = 0; xp < 7; xp++) dst[xp] = po[yi][xp];
    }
    __syncthreads();

    // phase 3b: coalesced copy-out, 16B/lane
    u16* gout = vlocB + ((size_t)b * DH_ + sub * 64) * N_;
    #pragma unroll
    for (int i = 0; i < 7; i++) {
        int g = i * 256 + tid;
        if (g < 1568)
            *(v8s*)&gout[g * 8] = *(const v8s*)&V[g * 8];
    }
}

// ---------------------------------------------------------------------------
// K3: score GEMM per (b,h), LDS-free; qI/kI rows are MFMA fragments
// ---------------------------------------------------------------------------
__global__ __launch_bounds__(256) void k_score(
    const u16* __restrict__ qI, const u16* __restrict__ kI,
    u16* __restrict__ Sh)
{
    const int tid = threadIdx.x;
    const int w = tid >> 6, lane = tid & 63;
    const int quad = lane >> 4, l16 = lane & 15;
    const int b = blockIdx.z, h = blockIdx.y;
    const int qt = blockIdx.x * 4 + w;
    if (qt >= 13) return;   // wave-uniform

    const u16* qb = qI + (size_t)(b * 8 + h) * 8192;
    const u16* kb = kI + (size_t)(b * 8 + h) * 8192;
    v8s a = *(const v8s*)&qb[(qt * 16 + l16) * 32 + quad * 8];
    const int q0 = qt * 16 + quad * 4;
    u16* So = Sh + (size_t)(b * 8 + h) * N_ * N_;

    for (int mt = 0; mt < 13; mt++) {
        v8s bfr = *(const v8s*)&kb[(mt * 16 + l16) * 32 + quad * 8];
        v4f acc = {};
        acc = __builtin_amdgcn_mfma_f32_16x16x32_bf16(a, bfr, acc, 0, 0, 0);
        int m = mt * 16 + l16;
        if (m < N_) {
            #pragma unroll
            for (int r = 0; r < 4; r++) {
                int q = q0 + r;
                if (q < N_) So[(size_t)q * N_ + m] = f2h(acc[r]);
            }
        }
    }
}

// ---------------------------------------------------------------------------
// K4: register-resident softmax/talking-heads -> P image
// ---------------------------------------------------------------------------
__global__ __launch_bounds__(256) void k_soft(
    const u16* __restrict__ Sh,
    const float* __restrict__ th1w, const float* __restrict__ th1b,
    const float* __restrict__ th2w, const float* __restrict__ th2b,
    const float* __restrict__ abT, const int* __restrict__ bidx,
    u16* __restrict__ PbI)
{
    __shared__ float red[2][4][8];
    const int tid = threadIdx.x;
    const int m = tid;
    const int w = tid >> 6;
    const int n = blockIdx.x, b = blockIdx.y;
    const bool act = (m < N_);

    float S[8];
    if (act) {
        int idx = bidx[n * N_ + m];
        v4f ab0 = *(const v4f*)&abT[idx * 8];
        v4f ab1 = *(const v4f*)&abT[idx * 8 + 4];
        #pragma unroll
        for (int h = 0; h < 8; h++) {
            float bias = (h < 4) ? ab0[h] : ab1[h - 4];
            S[h] = h2f(Sh[((size_t)(b * 8 + h) * N_ + n) * N_ + m]) + bias;
        }
    } else {
        #pragma unroll
        for (int h = 0; h < 8; h++) S[h] = 0.f;
    }

    float A[8];
    #pragma unroll
    for (int o = 0; o < 8; o++) {
        float a = th1b[o];
        #pragma unroll
        for (int h = 0; h < 8; h++) a += th1w[o * 8 + h] * S[h];
        A[o] = act ? a : -1e30f;
    }

    #pragma unroll
    for (int o = 0; o < 8; o++) {
        float v = A[o];
        #pragma unroll
        for (int off = 32; off > 0; off >>= 1) v = fmaxf(v, __shfl_xor(v, off, 64));
        if ((tid & 63) == 0) red[0][w][o] = v;
    }
    __syncthreads();
    float e[8];
    #pragma unroll
    for (int o = 0; o < 8; o++) {
        float mx = fmaxf(fmaxf(red[0][0][o], red[0][1][o]),
                         fmaxf(red[0][2][o], red[0][3][o]));
        e[o] = act ? __expf(A[o] - mx) : 0.f;
    }
    #pragma unroll
    for (int o = 0; o < 8; o++) {
        float v = e[o];
        #pragma unroll
        for (int off = 32; off > 0; off >>= 1) v += __shfl_xor(v, off, 64);
        if ((tid & 63) == 0) red[1][w][o] = v;
    }
    __syncthreads();
    #pragma unroll
    for (int o = 0; o < 8; o++) {
        float sm = (red[1][0][o] + red[1][1][o]) + (red[1][2][o] + red[1][3][o]);
        e[o] *= (1.f / sm);
    }
    if (m < 224) {
        size_t rowoff = ((size_t)(m >> 5)) * 4096 + ((m >> 3) & 3) * 1024 + (n & 127) * 8 + (m & 7);
        #pragma unroll
        for (int o = 0; o < 8; o++) {
            float p = th2b[o];
            #pragma unroll
            for (int h = 0; h < 8; h++) p += th2w[o * 8 + h] * e[h];
            PbI[((size_t)(b * 8 + o) * 2 + (n >> 7)) * 28672 + rowoff] = act ? f2bf(p) : (u16)0;
        }
    }
}

// ---------------------------------------------------------------------------
// K5: attn @ V (K=224, 7 ksteps) + v_local(bf16) + relu -> aoI image
// ---------------------------------------------------------------------------
__global__ __launch_bounds__(256) void k_av(
    const u16* __restrict__ vI, const u16* __restrict__ PbI,
    const u16* __restrict__ vlocB, u16* __restrict__ aoI)
{
    __shared__ u16 sA[4096];
    __shared__ u16 sB[4096];
    const int tid = threadIdx.x;
    const int nt = blockIdx.x;
    const int o  = blockIdx.y;
    const int b  = blockIdx.z;
    v4f acc[4][4] = {};
    gemm_core_g(vI + (size_t)(b * 8 + o) * 28672,
                PbI + ((size_t)(b * 8 + o) * 2 + nt) * 28672, 7, sA, sB, acc, tid);

    const int lane = tid & 63, w = tid >> 6;
    const int wm = (w & 1) * 64, wn = (w >> 1) * 64;
    const int quad = lane >> 4, l16 = lane & 15;
    #pragma unroll
    for (int i = 0; i < 4; i++) {
        #pragma unroll
        for (int j = 0; j < 4; j++) {
            int lr = wm + i * 16 + quad * 4;        // e base
            int c0 = o * 128 + lr;                  // global k-index base
            int n  = nt * 128 + wn + j * 16 + l16;  // token (0..255)
            v4u u;
            #pragma unroll
            for (int r = 0; r < 4; r++) {
                u16 outv = 0;
                if (n < N_) {
                    float val = acc[i][j][r] + bf2f(vlocB[((size_t)b * DH_ + c0 + r) * N_ + n]);
                    outv = f2bf(fmaxf(val, 0.f));
                }
                u[r] = outv;
            }
            *(v4u*)&aoI[((size_t)(b * 2 + nt) * 32 + (c0 >> 5)) * 4096
                        + ((c0 >> 3) & 3) * 1024 + (n & 127) * 8 + (c0 & 7)] = u;
        }
    }
}

// ---------------------------------------------------------------------------
// K6: projection GEMM (K=1024, 32 ksteps) + BN -> out fp32
// ---------------------------------------------------------------------------
__global__ __launch_bounds__(256) void k_proj(
    const u16* __restrict__ WpI, const u16* __restrict__ aoI,
    const float* __restrict__ TB, float* __restrict__ out)
{
    __shared__ u16 sA[4096];
    __shared__ u16 sB[4096];
    const int tid = threadIdx.x;
    const int nt = blockIdx.x;
    const int mt = blockIdx.y;
    const int b  = blockIdx.z;
    v4f acc[4][4] = {};
    gemm_core_g(WpI + (size_t)mt * 131072,
                aoI + (size_t)(b * 2 + nt) * 131072, 32, sA, sB, acc, tid);

    const int lane = tid & 63, w = tid >> 6;
    const int wm = (w & 1) * 64, wn = (w >> 1) * 64;
    const int quad = lane >> 4, l16 = lane & 15;
    #pragma unroll
    for (int i = 0; i < 4; i++) {
        #pragma unroll
        for (int j = 0; j < 4; j++) {
            int p0 = mt * 128 + wm + i * 16 + quad * 4;
            int n  = nt * 128 + wn + j * 16 + l16;
            if (n < N_) {
                v4f s = *(const v4f*)&TB[3072 + p0];
                v4f t = *(const v4f*)&TB[3456 + p0];
                #pragma unroll
                for (int r = 0; r < 4; r++)
                    out[((size_t)b * DIM_ + p0 + r) * N_ + n] = acc[i][j][r] * s[r] + t[r];
            }
        }
    }
}

// ---------------------------------------------------------------------------
extern "C" void kernel_launch(void* const* d_in, const int* in_sizes, int n_in,
                              void* d_out, int out_size, void* d_ws, size_t ws_size,
                              hipStream_t stream)
{
    const float* x    = (const float*)d_in[0];
    const float* wq   = (const float*)d_in[1];
    const float* bq   = (const float*)d_in[2];
    const float* bnq  = (const float*)d_in[3];
    const float* wk   = (const float*)d_in[4];
    const float* bk   = (const float*)d_in[5];
    const float* bnk  = (const float*)d_in[6];
    const float* wv   = (const float*)d_in[7];
    const float* bv   = (const float*)d_in[8];
    const float* bnv  = (const float*)d_in[9];
    const float* wvl  = (const float*)d_in[10];
    const float* bvl  = (const float*)d_in[11];
    const float* bnvl = (const float*)d_in[12];
    const float* th1w = (const float*)d_in[13];
    const float* th1b = (const float*)d_in[14];
    const float* th2w = (const float*)d_in[15];
    const float* th2b = (const float*)d_in[16];
    const float* wp   = (const float*)d_in[17];
    const float* bp   = (const float*)d_in[18];
    const float* bnp  = (const float*)d_in[19];
    const float* ab   = (const float*)d_in[20];
    const int*   bidx = (const int*)d_in[21];
    float* out = (float*)d_out;

    u16* wsb  = (u16*)d_ws;
    u16* WbI  = wsb + WBI_OFF;
    u16* WpI  = wsb + WPI_OFF;
    u16* qI   = wsb + QI_OFF;
    u16* kI   = wsb + KI_OFF;
    u16* vI   = wsb + VI_OFF;
    u16* PbI  = wsb + PBI_OFF;
    u16* vlocB = wsb + VLOC_U16;
    u16* xI   = wsb + TAIL_OFF;   // aliased: xI -> Sh -> aoI (disjoint lifetimes)
    u16* Sh   = wsb + TAIL_OFF;
    u16* aoI  = wsb + TAIL_OFF;
    float* TB  = (float*)(wsb + TB_OFF);
    float* abT = (float*)(wsb + ABT_OFF);

    k_castW<<<dim3(3859), 256, 0, stream>>>(wq, wk, wv, wp, ab,
                                            bq, bnq, bk, bnk, bv, bnv, bp, bnp, bvl, bnvl,
                                            WbI, WpI, abT, TB);
    k_castX<<<dim3(4, 6, B_), 256, 0, stream>>>(x, xI);
    k_qkv<<<dim3(2, 12, B_), 256, 0, stream>>>(WbI, xI, TB, qI, kI, vI);
    k_dwconv<<<dim3(16, B_), 256, 0, stream>>>(vI, wvl, TB, vlocB);
    k_score<<<dim3(4, HEADS_, B_), 256, 0, stream>>>(qI, kI, Sh);
    k_soft<<<dim3(N_, B_), 256, 0, stream>>>(Sh, th1w, th1b, th2w, th2b, abT, bidx, PbI);
    k_av<<<dim3(2, HEADS_, B_), 256, 0, stream>>>(vI, PbI, vlocB, aoI);
    k_proj<<<dim3(2, 3, B_), 256, 0, stream>>>(WpI, aoI, TB, out);
}